// Round 7
// baseline (543.731 us; speedup 1.0000x reference)
//
#include <hip/hip_runtime.h>

#define N_NODES 50000
#define N_EDGES_C 25000
#define NNZ_C 400000
#define SCHUNK 2048

typedef __bf16 bf16;
typedef __bf16 bf16x8 __attribute__((ext_vector_type(8)));
typedef __bf16 bf16x4 __attribute__((ext_vector_type(4)));
typedef float f32x4 __attribute__((ext_vector_type(4)));

typedef __attribute__((address_space(1))) const void as1_cvoid;
typedef __attribute__((address_space(3))) void as3_void;

__device__ __forceinline__ void gload_lds16(const bf16* g, bf16* l) {
  __builtin_amdgcn_global_load_lds((as1_cvoid*)g, (as3_void*)l, 16, 0, 0);
}

// ---------------- CSR build ----------------
__global__ void hist_kernel(const int* __restrict__ vtx, const int* __restrict__ edg,
                            int* __restrict__ cntV, int* __restrict__ cntE, int nnz) {
  int i = blockIdx.x * blockDim.x + threadIdx.x;
  if (i < nnz) {
    atomicAdd(&cntV[vtx[i]], 1);
    atomicAdd(&cntE[edg[i]], 1);
  }
}

__global__ void scan_part(const int* __restrict__ cnt, int* __restrict__ part, int n) {
  __shared__ int red[256];
  const int b = blockIdx.x, t = threadIdx.x;
  const int base = b * SCHUNK + t * 8;
  int s = 0;
#pragma unroll
  for (int q = 0; q < 8; ++q) {
    int i = base + q;
    if (i < n) s += cnt[i];
  }
  red[t] = s;
  __syncthreads();
  for (int d = 128; d > 0; d >>= 1) {
    if (t < d) red[t] += red[t + d];
    __syncthreads();
  }
  if (t == 0) part[b] = red[0];
}

__global__ void scan_mid(int* __restrict__ part, int* __restrict__ off, int nparts, int n) {
  const int lane = threadIdx.x;
  int orig = (lane < nparts) ? part[lane] : 0;
  int v = orig;
  for (int o = 1; o < 64; o <<= 1) {
    int x = __shfl_up(v, o);
    if (lane >= o) v += x;
  }
  if (lane < nparts) part[lane] = v - orig;
  if (lane == 63) off[n] = v;
}

__global__ void scan_final(const int* __restrict__ cnt, const int* __restrict__ part,
                           int* __restrict__ off, int n) {
  __shared__ int tsum[256];
  const int b = blockIdx.x, t = threadIdx.x;
  const int base = b * SCHUNK + t * 8;
  int loc[8];
  int s = 0;
#pragma unroll
  for (int q = 0; q < 8; ++q) {
    int i = base + q;
    loc[q] = (i < n) ? cnt[i] : 0;
    s += loc[q];
  }
  tsum[t] = s;
  __syncthreads();
  for (int d = 1; d < 256; d <<= 1) {
    int x = (t >= d) ? tsum[t - d] : 0;
    __syncthreads();
    tsum[t] += x;
    __syncthreads();
  }
  int run = part[b] + ((t > 0) ? tsum[t - 1] : 0);
#pragma unroll
  for (int q = 0; q < 8; ++q) {
    int i = base + q;
    if (i < n) off[i] = run;
    run += loc[q];
  }
}

__global__ void scatter_kernel(const int* __restrict__ vtx, const int* __restrict__ edg,
                               const int* __restrict__ eoff, const int* __restrict__ voff,
                               int* __restrict__ curE, int* __restrict__ curV,
                               int* __restrict__ evtx, int* __restrict__ vedg, int nnz) {
  int i = blockIdx.x * blockDim.x + threadIdx.x;
  if (i < nnz) {
    int e = edg[i], v = vtx[i];
    int p = atomicAdd(&curE[e], 1);
    evtx[eoff[e] + p] = v;
    int q = atomicAdd(&curV[v], 1);
    vedg[voff[v] + q] = e;
  }
}

// ---------------- conversions ----------------
__global__ void convert_f2b(const float* __restrict__ in, bf16* __restrict__ out, size_t n) {
  size_t i = ((size_t)blockIdx.x * blockDim.x + threadIdx.x) * 4;
  if (i >= n) return;
  float4 v = *(const float4*)(in + i);
  bf16x4 o;
  o[0] = (bf16)v.x; o[1] = (bf16)v.y; o[2] = (bf16)v.z; o[3] = (bf16)v.w;
  *(bf16x4*)(out + i) = o;
}

__global__ void transpose_w(const float* __restrict__ W, bf16* __restrict__ Wt,
                            int K, int N, int NtRows) {
  int idx = blockIdx.x * blockDim.x + threadIdx.x;
  int total = NtRows * K;
  if (idx >= total) return;
  int n = idx / K;
  int k = idx - n * K;
  Wt[idx] = (n < N) ? (bf16)W[(size_t)k * N + n] : (bf16)0.0f;
}

// ---------------- GEMM: BK=64, swizzled LDS, double-buffered counted-vmcnt pipeline ----------------
// 16B chunk c of row r lives at physical slot c^(r&7); global source carries the
// inverse permutation (gload_lds writes linearly), ds_read applies the same XOR.
// Pipeline: STAGE(t+1) -> s_waitcnt vmcnt(8) (tile t landed, t+1 in flight) ->
// raw s_barrier -> MFMA(t) -> s_barrier.  Never drains vmcnt to 0 mid-loop.
template <int BF16OUT>
__global__ __launch_bounds__(256) void gemm_bf16_kernel(
    const bf16* __restrict__ A, const bf16* __restrict__ B,
    float* __restrict__ Cf, bf16* __restrict__ Cb, int M, int K, int ldC, int Nstore) {
  __shared__ bf16 Al[2][128][64];
  __shared__ bf16 Bl[2][128][64];
  const int t = threadIdx.x;
  const int m0 = blockIdx.x * 128;
  const int n0 = blockIdx.y * 128;
  const int w = t >> 6, lane = t & 63;
  const int wr = w >> 1, wc = w & 1;
  const int lr = lane & 15;
  const int ls = lane >> 4;

  f32x4 acc[4][4];
#pragma unroll
  for (int m = 0; m < 4; ++m)
#pragma unroll
    for (int n = 0; n < 4; ++n) acc[m][n] = (f32x4){0.f, 0.f, 0.f, 0.f};

  const int srow8 = lane >> 3;                     // 0..7
  const int scol = ((lane & 7) ^ srow8) << 3;      // swizzled source chunk

  const bf16* Abase = A + (size_t)m0 * K;
  const bf16* Bbase = B + (size_t)n0 * K;

#define STAGE(tile, bsel)                                                        \
  {                                                                              \
    const int kk_ = (tile) * 64;                                                 \
    _Pragma("unroll")                                                            \
    for (int q = 0; q < 4; ++q) {                                                \
      const int row = w * 32 + q * 8 + srow8;                                    \
      gload_lds16(Abase + (size_t)row * K + kk_ + scol, &Al[bsel][w*32+q*8][0]); \
      gload_lds16(Bbase + (size_t)row * K + kk_ + scol, &Bl[bsel][w*32+q*8][0]); \
    }                                                                            \
  }

  const int NT = K >> 6;
  STAGE(0, 0);
  for (int tt = 0; tt < NT; ++tt) {
    const int cur = tt & 1;
    if (tt + 1 < NT) {
      STAGE(tt + 1, cur ^ 1);
      asm volatile("s_waitcnt vmcnt(8)" ::: "memory");
    } else {
      asm volatile("s_waitcnt vmcnt(0)" ::: "memory");
    }
    __builtin_amdgcn_s_barrier();
    __builtin_amdgcn_s_setprio(1);
#pragma unroll
    for (int ks = 0; ks < 2; ++ks) {
      bf16x8 af[4], bfr[4];
#pragma unroll
      for (int m = 0; m < 4; ++m) {
        const int R = wr * 64 + m * 16 + lr;
        af[m] = *(const bf16x8*)(&Al[cur][R][((ks * 4 + ls) ^ (lr & 7)) << 3]);
      }
#pragma unroll
      for (int n = 0; n < 4; ++n) {
        const int R = wc * 64 + n * 16 + lr;
        bfr[n] = *(const bf16x8*)(&Bl[cur][R][((ks * 4 + ls) ^ (lr & 7)) << 3]);
      }
#pragma unroll
      for (int m = 0; m < 4; ++m)
#pragma unroll
        for (int n = 0; n < 4; ++n)
          acc[m][n] = __builtin_amdgcn_mfma_f32_16x16x32_bf16(af[m], bfr[n], acc[m][n], 0, 0, 0);
    }
    __builtin_amdgcn_s_setprio(0);
    __builtin_amdgcn_s_barrier();
  }
#undef STAGE

  const int cr = (lane >> 4) << 2;  // C/D: col = lane&15, row = (lane>>4)*4 + i
  const int cc = lane & 15;
#pragma unroll
  for (int m = 0; m < 4; ++m) {
#pragma unroll
    for (int n = 0; n < 4; ++n) {
      int gc = n0 + wc * 64 + n * 16 + cc;
      if (gc >= Nstore) continue;
#pragma unroll
      for (int i = 0; i < 4; ++i) {
        int gr = m0 + wr * 64 + m * 16 + cr + i;
        if (gr < M) {
          if (BF16OUT) Cb[(size_t)gr * ldC + gc] = (bf16)acc[m][n][i];
          else         Cf[(size_t)gr * ldC + gc] = acc[m][n][i];
        }
      }
    }
  }
}

// ---------------- wave-per-edge aggregation (bf16, C=512), unroll-2 ----------------
__global__ __launch_bounds__(256) void edge_agg_w(
    const bf16* __restrict__ Y, const int* __restrict__ eoff, const int* __restrict__ evtx,
    const float* __restrict__ degE, bf16* __restrict__ Xe, int nE) {
  const int wv = (blockIdx.x * 256 + threadIdx.x) >> 6;
  if (wv >= nE) return;
  const int lane = threadIdx.x & 63;
  const int beg = eoff[wv], end = eoff[wv + 1];
  const int cnt = end - beg;
  const float scale = (cnt > 0) ? degE[wv] / (float)cnt : 0.f;
  float acc[8] = {0.f, 0.f, 0.f, 0.f, 0.f, 0.f, 0.f, 0.f};
  for (int base = beg; base < end; base += 64) {
    const int nb = min(64, end - base);
    int myidx = (lane < nb) ? evtx[base + lane] : 0;
    int j = 0;
    for (; j + 1 < nb; j += 2) {
      const int i0 = __shfl(myidx, j);
      const int i1 = __shfl(myidx, j + 1);
      bf16x8 v0 = *(const bf16x8*)(Y + (size_t)i0 * 512 + lane * 8);
      bf16x8 v1 = *(const bf16x8*)(Y + (size_t)i1 * 512 + lane * 8);
#pragma unroll
      for (int q = 0; q < 8; ++q) acc[q] += (float)v0[q] + (float)v1[q];
    }
    if (j < nb) {
      const int i0 = __shfl(myidx, j);
      bf16x8 v0 = *(const bf16x8*)(Y + (size_t)i0 * 512 + lane * 8);
#pragma unroll
      for (int q = 0; q < 8; ++q) acc[q] += (float)v0[q];
    }
  }
  bf16x8 o;
#pragma unroll
  for (int q = 0; q < 8; ++q) o[q] = (bf16)(acc[q] * scale);
  *(bf16x8*)(Xe + (size_t)wv * 512 + lane * 8) = o;
}

// ---------------- wave-per-vertex aggregation (bf16, relu, C=512), unroll-2 ----------------
__global__ __launch_bounds__(256) void vtx_agg_w(
    const bf16* __restrict__ Xe, const int* __restrict__ voff, const int* __restrict__ vedg,
    const float* __restrict__ degV, bf16* __restrict__ outB, int nV) {
  const int wv = (blockIdx.x * 256 + threadIdx.x) >> 6;
  if (wv >= nV) return;
  const int lane = threadIdx.x & 63;
  const int beg = voff[wv], end = voff[wv + 1];
  const float dv = degV[wv];
  float acc[8] = {0.f, 0.f, 0.f, 0.f, 0.f, 0.f, 0.f, 0.f};
  for (int base = beg; base < end; base += 64) {
    const int nb = min(64, end - base);
    int myidx = (lane < nb) ? vedg[base + lane] : 0;
    int j = 0;
    for (; j + 1 < nb; j += 2) {
      const int i0 = __shfl(myidx, j);
      const int i1 = __shfl(myidx, j + 1);
      bf16x8 v0 = *(const bf16x8*)(Xe + (size_t)i0 * 512 + lane * 8);
      bf16x8 v1 = *(const bf16x8*)(Xe + (size_t)i1 * 512 + lane * 8);
#pragma unroll
      for (int q = 0; q < 8; ++q) acc[q] += (float)v0[q] + (float)v1[q];
    }
    if (j < nb) {
      const int i0 = __shfl(myidx, j);
      bf16x8 v0 = *(const bf16x8*)(Xe + (size_t)i0 * 512 + lane * 8);
#pragma unroll
      for (int q = 0; q < 8; ++q) acc[q] += (float)v0[q];
    }
  }
  bf16x8 o;
#pragma unroll
  for (int q = 0; q < 8; ++q) o[q] = (bf16)fmaxf(acc[q] * dv, 0.f);
  *(bf16x8*)(outB + (size_t)wv * 512 + lane * 8) = o;
}

// ---------------- wave-per-edge aggregation f32 (layer 3, C=40) ----------------
__global__ __launch_bounds__(256) void edge_agg40_w(
    const float* __restrict__ Y, const int* __restrict__ eoff, const int* __restrict__ evtx,
    const float* __restrict__ degE, float* __restrict__ Xe, int nE) {
  const int wv = (blockIdx.x * 256 + threadIdx.x) >> 6;
  if (wv >= nE) return;
  const int lane = threadIdx.x & 63;
  const int beg = eoff[wv], end = eoff[wv + 1];
  const int cnt = end - beg;
  const float scale = (cnt > 0) ? degE[wv] / (float)cnt : 0.f;
  float a0 = 0.f;
  for (int base = beg; base < end; base += 64) {
    const int nb = min(64, end - base);
    int myidx = (lane < nb) ? evtx[base + lane] : 0;
    int j = 0;
    for (; j + 3 < nb; j += 4) {
      const int i0 = __shfl(myidx, j);
      const int i1 = __shfl(myidx, j + 1);
      const int i2 = __shfl(myidx, j + 2);
      const int i3 = __shfl(myidx, j + 3);
      if (lane < 40) {
        float x0 = Y[(size_t)i0 * 40 + lane];
        float x1 = Y[(size_t)i1 * 40 + lane];
        float x2 = Y[(size_t)i2 * 40 + lane];
        float x3 = Y[(size_t)i3 * 40 + lane];
        a0 += (x0 + x1) + (x2 + x3);
      }
    }
    for (; j < nb; ++j) {
      const int i0 = __shfl(myidx, j);
      if (lane < 40) a0 += Y[(size_t)i0 * 40 + lane];
    }
  }
  if (lane < 40) Xe[(size_t)wv * 40 + lane] = a0 * scale;
}

// ---------------- final vertex aggregation + log_softmax (C=40, wave-per-vertex) ----------------
__global__ __launch_bounds__(256) void vtx_agg_lsm(
    const float* __restrict__ Xe, const int* __restrict__ voff, const int* __restrict__ vedg,
    const float* __restrict__ degV, float* __restrict__ out, int nV) {
  const int wv = (blockIdx.x * 256 + threadIdx.x) >> 6;
  if (wv >= nV) return;
  const int lane = threadIdx.x & 63;
  const int beg = voff[wv], end = voff[wv + 1];
  const float dv = degV[wv];
  float a0 = 0.f;
  for (int base = beg; base < end; base += 64) {
    const int nb = min(64, end - base);
    int myidx = (lane < nb) ? vedg[base + lane] : 0;
    int j = 0;
    for (; j + 3 < nb; j += 4) {
      const int i0 = __shfl(myidx, j);
      const int i1 = __shfl(myidx, j + 1);
      const int i2 = __shfl(myidx, j + 2);
      const int i3 = __shfl(myidx, j + 3);
      if (lane < 40) {
        float x0 = Xe[(size_t)i0 * 40 + lane];
        float x1 = Xe[(size_t)i1 * 40 + lane];
        float x2 = Xe[(size_t)i2 * 40 + lane];
        float x3 = Xe[(size_t)i3 * 40 + lane];
        a0 += (x0 + x1) + (x2 + x3);
      }
    }
    for (; j < nb; ++j) {
      const int i0 = __shfl(myidx, j);
      if (lane < 40) a0 += Xe[(size_t)i0 * 40 + lane];
    }
  }
  a0 *= dv;
  float val = (lane < 40) ? a0 : -3.4e38f;
  float m = val;
#pragma unroll
  for (int o = 32; o > 0; o >>= 1) m = fmaxf(m, __shfl_xor(m, o));
  float ex = (lane < 40) ? expf(val - m) : 0.f;
  float s = ex;
#pragma unroll
  for (int o = 32; o > 0; o >>= 1) s += __shfl_xor(s, o);
  float ls = logf(s);
  if (lane < 40) out[(size_t)wv * 40 + lane] = val - m - ls;
}

extern "C" void kernel_launch(void* const* d_in, const int* in_sizes, int n_in,
                              void* d_out, int out_size, void* d_ws, size_t ws_size,
                              hipStream_t stream) {
  (void)in_sizes; (void)n_in; (void)out_size; (void)ws_size;
  const float* X = (const float*)d_in[0];
  const int* vertex = (const int*)d_in[1];
  const int* edges = (const int*)d_in[2];
  const float* W1 = (const float*)d_in[3];
  const float* W2 = (const float*)d_in[4];
  const float* Wout = (const float*)d_in[5];
  const float* degE = (const float*)d_in[6];
  const float* degV = (const float*)d_in[7];
  float* out = (float*)d_out;

  char* ws = (char*)d_ws;
  size_t off = 0;
  auto alloc = [&](size_t bytes) -> void* {
    void* p = ws + off;
    off += (bytes + 255) & ~(size_t)255;
    return p;
  };
  bf16* Xb  = (bf16*)alloc((size_t)N_NODES * 512 * sizeof(bf16));
  bf16* Yb  = (bf16*)alloc((size_t)N_NODES * 512 * sizeof(bf16));
  bf16* XeB = (bf16*)alloc((size_t)N_EDGES_C * 512 * sizeof(bf16));
  float* Y40  = (float*)alloc((size_t)N_NODES * 40 * sizeof(float));
  float* Xe40 = (float*)alloc((size_t)N_EDGES_C * 40 * sizeof(float));
  bf16* Wt  = (bf16*)alloc((size_t)512 * 512 * sizeof(bf16));
  int* eoff = (int*)alloc((N_EDGES_C + 1) * sizeof(int));
  int* voff = (int*)alloc((N_NODES + 1) * sizeof(int));
  int* evtx = (int*)alloc((size_t)NNZ_C * sizeof(int));
  int* vedg = (int*)alloc((size_t)NNZ_C * sizeof(int));
  int* cntE = (int*)alloc(N_EDGES_C * sizeof(int));
  int* cntV = (int*)alloc(N_NODES * sizeof(int));
  int* curE = (int*)alloc(N_EDGES_C * sizeof(int));
  int* curV = (int*)alloc(N_NODES * sizeof(int));
  int* partE = (int*)alloc(64 * sizeof(int));
  int* partV = (int*)alloc(64 * sizeof(int));

  hipMemsetAsync(cntE, 0, N_EDGES_C * sizeof(int), stream);
  hipMemsetAsync(cntV, 0, N_NODES * sizeof(int), stream);
  hipMemsetAsync(curE, 0, N_EDGES_C * sizeof(int), stream);
  hipMemsetAsync(curV, 0, N_NODES * sizeof(int), stream);

  hist_kernel<<<(NNZ_C + 255) / 256, 256, 0, stream>>>(vertex, edges, cntV, cntE, NNZ_C);

  const int nbE = (N_EDGES_C + SCHUNK - 1) / SCHUNK;
  const int nbV = (N_NODES + SCHUNK - 1) / SCHUNK;
  scan_part<<<nbE, 256, 0, stream>>>(cntE, partE, N_EDGES_C);
  scan_mid<<<1, 64, 0, stream>>>(partE, eoff, nbE, N_EDGES_C);
  scan_final<<<nbE, 256, 0, stream>>>(cntE, partE, eoff, N_EDGES_C);
  scan_part<<<nbV, 256, 0, stream>>>(cntV, partV, N_NODES);
  scan_mid<<<1, 64, 0, stream>>>(partV, voff, nbV, N_NODES);
  scan_final<<<nbV, 256, 0, stream>>>(cntV, partV, voff, N_NODES);

  scatter_kernel<<<(NNZ_C + 255) / 256, 256, 0, stream>>>(vertex, edges, eoff, voff,
                                                          curE, curV, evtx, vedg, NNZ_C);

  convert_f2b<<<(N_NODES * 512 / 4 + 255) / 256, 256, 0, stream>>>(X, Xb, (size_t)N_NODES * 512);

  const int MB = (N_NODES + 127) / 128;

  // ---- layer 1 ----
  transpose_w<<<(512 * 512 + 255) / 256, 256, 0, stream>>>(W1, Wt, 512, 512, 512);
  {
    dim3 g(MB, 4);
    gemm_bf16_kernel<1><<<g, 256, 0, stream>>>(Xb, Wt, nullptr, Yb, N_NODES, 512, 512, 512);
  }
  edge_agg_w<<<(N_EDGES_C + 3) / 4, 256, 0, stream>>>(Yb, eoff, evtx, degE, XeB, N_EDGES_C);
  vtx_agg_w<<<(N_NODES + 3) / 4, 256, 0, stream>>>(XeB, voff, vedg, degV, Xb, N_NODES);

  // ---- layer 2 ----
  transpose_w<<<(512 * 512 + 255) / 256, 256, 0, stream>>>(W2, Wt, 512, 512, 512);
  {
    dim3 g(MB, 4);
    gemm_bf16_kernel<1><<<g, 256, 0, stream>>>(Xb, Wt, nullptr, Yb, N_NODES, 512, 512, 512);
  }
  edge_agg_w<<<(N_EDGES_C + 3) / 4, 256, 0, stream>>>(Yb, eoff, evtx, degE, XeB, N_EDGES_C);
  vtx_agg_w<<<(N_NODES + 3) / 4, 256, 0, stream>>>(XeB, voff, vedg, degV, Xb, N_NODES);

  // ---- layer 3 (C=40) ----
  transpose_w<<<(128 * 512 + 255) / 256, 256, 0, stream>>>(Wout, Wt, 512, 40, 128);
  {
    dim3 g(MB, 1);
    gemm_bf16_kernel<0><<<g, 256, 0, stream>>>(Xb, Wt, Y40, nullptr, N_NODES, 512, 40, 40);
  }
  edge_agg40_w<<<(N_EDGES_C + 3) / 4, 256, 0, stream>>>(Y40, eoff, evtx, degE, Xe40, N_EDGES_C);
  vtx_agg_lsm<<<(N_NODES + 3) / 4, 256, 0, stream>>>(Xe40, voff, vedg, degV, out, N_NODES);
}

// Round 8
// 518.969 us; speedup vs baseline: 1.0477x; 1.0477x over previous
//
#include <hip/hip_runtime.h>

#define N_NODES 50000
#define N_EDGES_C 25000
#define NNZ_C 400000
#define SCHUNK 2048

typedef __bf16 bf16;
typedef __bf16 bf16x8 __attribute__((ext_vector_type(8)));
typedef __bf16 bf16x4 __attribute__((ext_vector_type(4)));
typedef float f32x4 __attribute__((ext_vector_type(4)));

typedef __attribute__((address_space(1))) const void as1_cvoid;
typedef __attribute__((address_space(3))) void as3_void;

__device__ __forceinline__ void gload_lds16(const bf16* g, bf16* l) {
  __builtin_amdgcn_global_load_lds((as1_cvoid*)g, (as3_void*)l, 16, 0, 0);
}

// ---------------- CSR build ----------------
__global__ void hist_kernel(const int* __restrict__ vtx, const int* __restrict__ edg,
                            int* __restrict__ cntV, int* __restrict__ cntE, int nnz) {
  int i = blockIdx.x * blockDim.x + threadIdx.x;
  if (i < nnz) {
    atomicAdd(&cntV[vtx[i]], 1);
    atomicAdd(&cntE[edg[i]], 1);
  }
}

// combined E+V per-block partial sums
__global__ void scan_part2(const int* __restrict__ cntE, const int* __restrict__ cntV,
                           int* __restrict__ partE, int* __restrict__ partV,
                           int nbE) {
  __shared__ int red[256];
  const int t = threadIdx.x;
  const int isV = (blockIdx.x >= nbE);
  const int b = isV ? (blockIdx.x - nbE) : blockIdx.x;
  const int* cnt = isV ? cntV : cntE;
  const int n = isV ? N_NODES : N_EDGES_C;
  const int base = b * SCHUNK + t * 8;
  int s = 0;
#pragma unroll
  for (int q = 0; q < 8; ++q) {
    int i = base + q;
    if (i < n) s += cnt[i];
  }
  red[t] = s;
  __syncthreads();
  for (int d = 128; d > 0; d >>= 1) {
    if (t < d) red[t] += red[t + d];
    __syncthreads();
  }
  if (t == 0) (isV ? partV : partE)[b] = red[0];
}

// combined mid scan: wave 0 = E, wave 1 = V
__global__ void scan_mid2(int* __restrict__ partE, int* __restrict__ partV,
                          int* __restrict__ eoff, int* __restrict__ voff,
                          int nbE, int nbV) {
  const int wv = threadIdx.x >> 6;
  const int lane = threadIdx.x & 63;
  int* part = wv ? partV : partE;
  int* off = wv ? voff : eoff;
  const int np = wv ? nbV : nbE;
  const int n = wv ? N_NODES : N_EDGES_C;
  int orig = (lane < np) ? part[lane] : 0;
  int v = orig;
  for (int o = 1; o < 64; o <<= 1) {
    int x = __shfl_up(v, o);
    if (lane >= o) v += x;
  }
  if (lane < np) part[lane] = v - orig;
  if (lane == 63) off[n] = v;
}

__global__ void scan_final2(const int* __restrict__ cntE, const int* __restrict__ cntV,
                            const int* __restrict__ partE, const int* __restrict__ partV,
                            int* __restrict__ eoff, int* __restrict__ voff, int nbE) {
  __shared__ int tsum[256];
  const int t = threadIdx.x;
  const int isV = (blockIdx.x >= nbE);
  const int b = isV ? (blockIdx.x - nbE) : blockIdx.x;
  const int* cnt = isV ? cntV : cntE;
  const int* part = isV ? partV : partE;
  int* off = isV ? voff : eoff;
  const int n = isV ? N_NODES : N_EDGES_C;
  const int base = b * SCHUNK + t * 8;
  int loc[8];
  int s = 0;
#pragma unroll
  for (int q = 0; q < 8; ++q) {
    int i = base + q;
    loc[q] = (i < n) ? cnt[i] : 0;
    s += loc[q];
  }
  tsum[t] = s;
  __syncthreads();
  for (int d = 1; d < 256; d <<= 1) {
    int x = (t >= d) ? tsum[t - d] : 0;
    __syncthreads();
    tsum[t] += x;
    __syncthreads();
  }
  int run = part[b] + ((t > 0) ? tsum[t - 1] : 0);
#pragma unroll
  for (int q = 0; q < 8; ++q) {
    int i = base + q;
    if (i < n) off[i] = run;
    run += loc[q];
  }
}

__global__ void scatter_kernel(const int* __restrict__ vtx, const int* __restrict__ edg,
                               const int* __restrict__ eoff, const int* __restrict__ voff,
                               int* __restrict__ curE, int* __restrict__ curV,
                               int* __restrict__ evtx, int* __restrict__ vedg, int nnz) {
  int i = blockIdx.x * blockDim.x + threadIdx.x;
  if (i < nnz) {
    int e = edg[i], v = vtx[i];
    int p = atomicAdd(&curE[e], 1);
    evtx[eoff[e] + p] = v;
    int q = atomicAdd(&curV[v], 1);
    vedg[voff[v] + q] = e;
  }
}

// ---------------- prep: all 3 weight transposes in one launch ----------------
// Wt[n][k] = (n < N) ? W[k][n] : 0
__global__ void prep_kernel(const float* __restrict__ W1, const float* __restrict__ W2,
                            const float* __restrict__ Wout,
                            bf16* __restrict__ Wt1, bf16* __restrict__ Wt2,
                            bf16* __restrict__ Wt3) {
  int b = blockIdx.x;
  const int t = threadIdx.x;
  if (b < 1024) {  // W1: 512x512
    int idx = b * 256 + t;
    int n = idx >> 9, k = idx & 511;
    Wt1[idx] = (bf16)W1[(size_t)k * 512 + n];
  } else if (b < 2048) {  // W2: 512x512
    int idx = (b - 1024) * 256 + t;
    int n = idx >> 9, k = idx & 511;
    Wt2[idx] = (bf16)W2[(size_t)k * 512 + n];
  } else {  // Wout: 128 rows x 512, N=40 pad
    int idx = (b - 2048) * 256 + t;
    int n = idx >> 9, k = idx & 511;
    Wt3[idx] = (n < 40) ? (bf16)Wout[(size_t)k * 40 + n] : (bf16)0.0f;
  }
}

// ---------------- GEMM (bf16 A): BK=64, swizzled LDS, dbuf counted-vmcnt ----------------
// grid(NB, MB): x = n-block (4 consecutive blocks share the A tile -> L2/L3 reuse)
template <int BF16OUT>
__global__ __launch_bounds__(256) void gemm_bf16_kernel(
    const bf16* __restrict__ A, const bf16* __restrict__ B,
    float* __restrict__ Cf, bf16* __restrict__ Cb, int M, int K, int ldC, int Nstore) {
  __shared__ bf16 Al[2][128][64];
  __shared__ bf16 Bl[2][128][64];
  const int t = threadIdx.x;
  const int n0 = blockIdx.x * 128;
  const int m0 = blockIdx.y * 128;
  const int w = t >> 6, lane = t & 63;
  const int wr = w >> 1, wc = w & 1;
  const int lr = lane & 15;
  const int ls = lane >> 4;

  f32x4 acc[4][4];
#pragma unroll
  for (int m = 0; m < 4; ++m)
#pragma unroll
    for (int n = 0; n < 4; ++n) acc[m][n] = (f32x4){0.f, 0.f, 0.f, 0.f};

  const int srow8 = lane >> 3;
  const int scol = ((lane & 7) ^ srow8) << 3;

  const bf16* Abase = A + (size_t)m0 * K;
  const bf16* Bbase = B + (size_t)n0 * K;

#define STAGE(tile, bsel)                                                        \
  {                                                                              \
    const int kk_ = (tile) * 64;                                                 \
    _Pragma("unroll")                                                            \
    for (int q = 0; q < 4; ++q) {                                                \
      const int row = w * 32 + q * 8 + srow8;                                    \
      gload_lds16(Abase + (size_t)row * K + kk_ + scol, &Al[bsel][w*32+q*8][0]); \
      gload_lds16(Bbase + (size_t)row * K + kk_ + scol, &Bl[bsel][w*32+q*8][0]); \
    }                                                                            \
  }

  const int NT = K >> 6;
  STAGE(0, 0);
  for (int tt = 0; tt < NT; ++tt) {
    const int cur = tt & 1;
    if (tt + 1 < NT) {
      STAGE(tt + 1, cur ^ 1);
      asm volatile("s_waitcnt vmcnt(8)" ::: "memory");
    } else {
      asm volatile("s_waitcnt vmcnt(0)" ::: "memory");
    }
    __builtin_amdgcn_s_barrier();
    __builtin_amdgcn_s_setprio(1);
#pragma unroll
    for (int ks = 0; ks < 2; ++ks) {
      bf16x8 af[4], bfr[4];
#pragma unroll
      for (int m = 0; m < 4; ++m) {
        const int R = wr * 64 + m * 16 + lr;
        af[m] = *(const bf16x8*)(&Al[cur][R][((ks * 4 + ls) ^ (lr & 7)) << 3]);
      }
#pragma unroll
      for (int n = 0; n < 4; ++n) {
        const int R = wc * 64 + n * 16 + lr;
        bfr[n] = *(const bf16x8*)(&Bl[cur][R][((ks * 4 + ls) ^ (lr & 7)) << 3]);
      }
#pragma unroll
      for (int m = 0; m < 4; ++m)
#pragma unroll
        for (int n = 0; n < 4; ++n)
          acc[m][n] = __builtin_amdgcn_mfma_f32_16x16x32_bf16(af[m], bfr[n], acc[m][n], 0, 0, 0);
    }
    __builtin_amdgcn_s_setprio(0);
    __builtin_amdgcn_s_barrier();
  }
#undef STAGE

  const int cr = (lane >> 4) << 2;  // C/D: col = lane&15, row = (lane>>4)*4 + i
  const int cc = lane & 15;
#pragma unroll
  for (int m = 0; m < 4; ++m) {
#pragma unroll
    for (int n = 0; n < 4; ++n) {
      int gc = n0 + wc * 64 + n * 16 + cc;
      if (gc >= Nstore) continue;
#pragma unroll
      for (int i = 0; i < 4; ++i) {
        int gr = m0 + wr * 64 + m * 16 + cr + i;
        if (gr < M) {
          if (BF16OUT) Cb[(size_t)gr * ldC + gc] = (bf16)acc[m][n][i];
          else         Cf[(size_t)gr * ldC + gc] = acc[m][n][i];
        }
      }
    }
  }
}

// ---------------- GEMM layer-1 (f32 A, fused convert): reg-stage A -> cvt -> swizzled ds_write ----------------
__global__ __launch_bounds__(256) void gemm_af32_kernel(
    const float* __restrict__ Af, const bf16* __restrict__ B,
    bf16* __restrict__ Cb, int M, int K, int ldC) {
  __shared__ bf16 Al[2][128][64];
  __shared__ bf16 Bl[2][128][64];
  const int t = threadIdx.x;
  const int n0 = blockIdx.x * 128;
  const int m0 = blockIdx.y * 128;
  const int w = t >> 6, lane = t & 63;
  const int wr = w >> 1, wc = w & 1;
  const int lr = lane & 15;
  const int ls = lane >> 4;

  f32x4 acc[4][4];
#pragma unroll
  for (int m = 0; m < 4; ++m)
#pragma unroll
    for (int n = 0; n < 4; ++n) acc[m][n] = (f32x4){0.f, 0.f, 0.f, 0.f};

  // A staging map: thread handles rows r0+32q (q=0..3), logical chunk cc (8 f32 -> 8 bf16)
  const int cc_ = t & 7;
  const int r0 = t >> 3;                 // 0..31
  const int physc = cc_ ^ (r0 & 7);      // swizzled 16B slot
  // B staging (gload_lds, pre-swizzled source)
  const int srow8 = lane >> 3;
  const int scol = ((lane & 7) ^ srow8) << 3;
  const bf16* Bbase = B + (size_t)n0 * K;

  float4 fa[4], fb[4];

#define AISSUE(tile)                                                   \
  { const int kk_ = (tile) * 64;                                       \
    _Pragma("unroll") for (int q = 0; q < 4; ++q) {                    \
      int grow = m0 + r0 + 32 * q; if (grow > M - 1) grow = M - 1;     \
      const float* p = Af + (size_t)grow * K + kk_ + cc_ * 8;          \
      fa[q] = *(const float4*)p;                                       \
      fb[q] = *(const float4*)(p + 4); } }

#define AWRITE(bsel)                                                   \
  { _Pragma("unroll") for (int q = 0; q < 4; ++q) {                    \
      bf16x8 cv;                                                       \
      cv[0] = (bf16)fa[q].x; cv[1] = (bf16)fa[q].y;                    \
      cv[2] = (bf16)fa[q].z; cv[3] = (bf16)fa[q].w;                    \
      cv[4] = (bf16)fb[q].x; cv[5] = (bf16)fb[q].y;                    \
      cv[6] = (bf16)fb[q].z; cv[7] = (bf16)fb[q].w;                    \
      *(bf16x8*)(&Al[bsel][r0 + 32 * q][physc * 8]) = cv; } }

#define BSTAGE(tile, bsel)                                                       \
  { const int kk_ = (tile) * 64;                                                 \
    _Pragma("unroll") for (int q = 0; q < 4; ++q) {                              \
      const int row = w * 32 + q * 8 + srow8;                                    \
      gload_lds16(Bbase + (size_t)row * K + kk_ + scol, &Bl[bsel][w*32+q*8][0]); \
    } }

  const int NT = K >> 6;
  // prologue: A(0) loads [8], B(0) gload [4] -> wait A, write A
  AISSUE(0);
  __builtin_amdgcn_sched_barrier(0);
  BSTAGE(0, 0);
  __builtin_amdgcn_sched_barrier(0);
  asm volatile("s_waitcnt vmcnt(4)" ::: "memory");  // A(0) done, B(0) in flight
  AWRITE(0);
  asm volatile("s_waitcnt lgkmcnt(0)" ::: "memory");

  for (int tt = 0; tt < NT; ++tt) {
    const int cur = tt & 1;
    if (tt + 1 < NT) {
      AISSUE(tt + 1);                     // 8 loads
      __builtin_amdgcn_sched_barrier(0);
      BSTAGE(tt + 1, cur ^ 1);            // 4 gload_lds
      __builtin_amdgcn_sched_barrier(0);
      asm volatile("s_waitcnt vmcnt(12)" ::: "memory");  // retire B(t) (4 oldest)
    } else {
      asm volatile("s_waitcnt vmcnt(0)" ::: "memory");
    }
    __builtin_amdgcn_s_barrier();
    __builtin_amdgcn_s_setprio(1);
#pragma unroll
    for (int ks = 0; ks < 2; ++ks) {
      bf16x8 af[4], bfr[4];
#pragma unroll
      for (int m = 0; m < 4; ++m) {
        const int R = wr * 64 + m * 16 + lr;
        af[m] = *(const bf16x8*)(&Al[cur][R][((ks * 4 + ls) ^ (lr & 7)) << 3]);
      }
#pragma unroll
      for (int n = 0; n < 4; ++n) {
        const int R = wc * 64 + n * 16 + lr;
        bfr[n] = *(const bf16x8*)(&Bl[cur][R][((ks * 4 + ls) ^ (lr & 7)) << 3]);
      }
#pragma unroll
      for (int m = 0; m < 4; ++m)
#pragma unroll
        for (int n = 0; n < 4; ++n)
          acc[m][n] = __builtin_amdgcn_mfma_f32_16x16x32_bf16(af[m], bfr[n], acc[m][n], 0, 0, 0);
    }
    __builtin_amdgcn_s_setprio(0);
    if (tt + 1 < NT) {
      asm volatile("s_waitcnt vmcnt(4)" ::: "memory");  // A(t+1) landed (B(t+1) may fly)
      AWRITE(cur ^ 1);
      asm volatile("s_waitcnt lgkmcnt(0)" ::: "memory");
    }
    __builtin_amdgcn_s_barrier();
  }
#undef AISSUE
#undef AWRITE
#undef BSTAGE

  const int cr = (lane >> 4) << 2;
  const int cc = lane & 15;
#pragma unroll
  for (int m = 0; m < 4; ++m) {
#pragma unroll
    for (int n = 0; n < 4; ++n) {
      int gc = n0 + wc * 64 + n * 16 + cc;
#pragma unroll
      for (int i = 0; i < 4; ++i) {
        int gr = m0 + wr * 64 + m * 16 + cr + i;
        if (gr < M) Cb[(size_t)gr * ldC + gc] = (bf16)acc[m][n][i];
      }
    }
  }
}

// ---------------- wave-per-edge aggregation (bf16, C=512), unroll-2 ----------------
__global__ __launch_bounds__(256) void edge_agg_w(
    const bf16* __restrict__ Y, const int* __restrict__ eoff, const int* __restrict__ evtx,
    const float* __restrict__ degE, bf16* __restrict__ Xe, int nE) {
  const int wv = (blockIdx.x * 256 + threadIdx.x) >> 6;
  if (wv >= nE) return;
  const int lane = threadIdx.x & 63;
  const int beg = eoff[wv], end = eoff[wv + 1];
  const int cnt = end - beg;
  const float scale = (cnt > 0) ? degE[wv] / (float)cnt : 0.f;
  float acc[8] = {0.f, 0.f, 0.f, 0.f, 0.f, 0.f, 0.f, 0.f};
  for (int base = beg; base < end; base += 64) {
    const int nb = min(64, end - base);
    int myidx = (lane < nb) ? evtx[base + lane] : 0;
    int j = 0;
    for (; j + 1 < nb; j += 2) {
      const int i0 = __shfl(myidx, j);
      const int i1 = __shfl(myidx, j + 1);
      bf16x8 v0 = *(const bf16x8*)(Y + (size_t)i0 * 512 + lane * 8);
      bf16x8 v1 = *(const bf16x8*)(Y + (size_t)i1 * 512 + lane * 8);
#pragma unroll
      for (int q = 0; q < 8; ++q) acc[q] += (float)v0[q] + (float)v1[q];
    }
    if (j < nb) {
      const int i0 = __shfl(myidx, j);
      bf16x8 v0 = *(const bf16x8*)(Y + (size_t)i0 * 512 + lane * 8);
#pragma unroll
      for (int q = 0; q < 8; ++q) acc[q] += (float)v0[q];
    }
  }
  bf16x8 o;
#pragma unroll
  for (int q = 0; q < 8; ++q) o[q] = (bf16)(acc[q] * scale);
  *(bf16x8*)(Xe + (size_t)wv * 512 + lane * 8) = o;
}

// ---------------- wave-per-vertex aggregation (bf16, relu, C=512), unroll-2 ----------------
__global__ __launch_bounds__(256) void vtx_agg_w(
    const bf16* __restrict__ Xe, const int* __restrict__ voff, const int* __restrict__ vedg,
    const float* __restrict__ degV, bf16* __restrict__ outB, int nV) {
  const int wv = (blockIdx.x * 256 + threadIdx.x) >> 6;
  if (wv >= nV) return;
  const int lane = threadIdx.x & 63;
  const int beg = voff[wv], end = voff[wv + 1];
  const float dv = degV[wv];
  float acc[8] = {0.f, 0.f, 0.f, 0.f, 0.f, 0.f, 0.f, 0.f};
  for (int base = beg; base < end; base += 64) {
    const int nb = min(64, end - base);
    int myidx = (lane < nb) ? vedg[base + lane] : 0;
    int j = 0;
    for (; j + 1 < nb; j += 2) {
      const int i0 = __shfl(myidx, j);
      const int i1 = __shfl(myidx, j + 1);
      bf16x8 v0 = *(const bf16x8*)(Xe + (size_t)i0 * 512 + lane * 8);
      bf16x8 v1 = *(const bf16x8*)(Xe + (size_t)i1 * 512 + lane * 8);
#pragma unroll
      for (int q = 0; q < 8; ++q) acc[q] += (float)v0[q] + (float)v1[q];
    }
    if (j < nb) {
      const int i0 = __shfl(myidx, j);
      bf16x8 v0 = *(const bf16x8*)(Xe + (size_t)i0 * 512 + lane * 8);
#pragma unroll
      for (int q = 0; q < 8; ++q) acc[q] += (float)v0[q];
    }
  }
  bf16x8 o;
#pragma unroll
  for (int q = 0; q < 8; ++q) o[q] = (bf16)fmaxf(acc[q] * dv, 0.f);
  *(bf16x8*)(outB + (size_t)wv * 512 + lane * 8) = o;
}

// ---------------- wave-per-edge aggregation f32 (layer 3, C=40) ----------------
__global__ __launch_bounds__(256) void edge_agg40_w(
    const float* __restrict__ Y, const int* __restrict__ eoff, const int* __restrict__ evtx,
    const float* __restrict__ degE, float* __restrict__ Xe, int nE) {
  const int wv = (blockIdx.x * 256 + threadIdx.x) >> 6;
  if (wv >= nE) return;
  const int lane = threadIdx.x & 63;
  const int beg = eoff[wv], end = eoff[wv + 1];
  const int cnt = end - beg;
  const float scale = (cnt > 0) ? degE[wv] / (float)cnt : 0.f;
  float a0 = 0.f;
  for (int base = beg; base < end; base += 64) {
    const int nb = min(64, end - base);
    int myidx = (lane < nb) ? evtx[base + lane] : 0;
    int j = 0;
    for (; j + 3 < nb; j += 4) {
      const int i0 = __shfl(myidx, j);
      const int i1 = __shfl(myidx, j + 1);
      const int i2 = __shfl(myidx, j + 2);
      const int i3 = __shfl(myidx, j + 3);
      if (lane < 40) {
        float x0 = Y[(size_t)i0 * 40 + lane];
        float x1 = Y[(size_t)i1 * 40 + lane];
        float x2 = Y[(size_t)i2 * 40 + lane];
        float x3 = Y[(size_t)i3 * 40 + lane];
        a0 += (x0 + x1) + (x2 + x3);
      }
    }
    for (; j < nb; ++j) {
      const int i0 = __shfl(myidx, j);
      if (lane < 40) a0 += Y[(size_t)i0 * 40 + lane];
    }
  }
  if (lane < 40) Xe[(size_t)wv * 40 + lane] = a0 * scale;
}

// ---------------- final vertex aggregation + log_softmax (C=40) ----------------
__global__ __launch_bounds__(256) void vtx_agg_lsm(
    const float* __restrict__ Xe, const int* __restrict__ voff, const int* __restrict__ vedg,
    const float* __restrict__ degV, float* __restrict__ out, int nV) {
  const int wv = (blockIdx.x * 256 + threadIdx.x) >> 6;
  if (wv >= nV) return;
  const int lane = threadIdx.x & 63;
  const int beg = voff[wv], end = voff[wv + 1];
  const float dv = degV[wv];
  float a0 = 0.f;
  for (int base = beg; base < end; base += 64) {
    const int nb = min(64, end - base);
    int myidx = (lane < nb) ? vedg[base + lane] : 0;
    int j = 0;
    for (; j + 3 < nb; j += 4) {
      const int i0 = __shfl(myidx, j);
      const int i1 = __shfl(myidx, j + 1);
      const int i2 = __shfl(myidx, j + 2);
      const int i3 = __shfl(myidx, j + 3);
      if (lane < 40) {
        float x0 = Xe[(size_t)i0 * 40 + lane];
        float x1 = Xe[(size_t)i1 * 40 + lane];
        float x2 = Xe[(size_t)i2 * 40 + lane];
        float x3 = Xe[(size_t)i3 * 40 + lane];
        a0 += (x0 + x1) + (x2 + x3);
      }
    }
    for (; j < nb; ++j) {
      const int i0 = __shfl(myidx, j);
      if (lane < 40) a0 += Xe[(size_t)i0 * 40 + lane];
    }
  }
  a0 *= dv;
  float val = (lane < 40) ? a0 : -3.4e38f;
  float m = val;
#pragma unroll
  for (int o = 32; o > 0; o >>= 1) m = fmaxf(m, __shfl_xor(m, o));
  float ex = (lane < 40) ? expf(val - m) : 0.f;
  float s = ex;
#pragma unroll
  for (int o = 32; o > 0; o >>= 1) s += __shfl_xor(s, o);
  float ls = logf(s);
  if (lane < 40) out[(size_t)wv * 40 + lane] = val - m - ls;
}

extern "C" void kernel_launch(void* const* d_in, const int* in_sizes, int n_in,
                              void* d_out, int out_size, void* d_ws, size_t ws_size,
                              hipStream_t stream) {
  (void)in_sizes; (void)n_in; (void)out_size; (void)ws_size;
  const float* X = (const float*)d_in[0];
  const int* vertex = (const int*)d_in[1];
  const int* edges = (const int*)d_in[2];
  const float* W1 = (const float*)d_in[3];
  const float* W2 = (const float*)d_in[4];
  const float* Wout = (const float*)d_in[5];
  const float* degE = (const float*)d_in[6];
  const float* degV = (const float*)d_in[7];
  float* out = (float*)d_out;

  char* ws = (char*)d_ws;
  size_t off = 0;
  auto alloc = [&](size_t bytes) -> void* {
    void* p = ws + off;
    off += (bytes + 255) & ~(size_t)255;
    return p;
  };
  bf16* Xb  = (bf16*)alloc((size_t)N_NODES * 512 * sizeof(bf16));
  bf16* Yb  = (bf16*)alloc((size_t)N_NODES * 512 * sizeof(bf16));
  bf16* XeB = (bf16*)alloc((size_t)N_EDGES_C * 512 * sizeof(bf16));
  float* Y40  = (float*)alloc((size_t)N_NODES * 40 * sizeof(float));
  float* Xe40 = (float*)alloc((size_t)N_EDGES_C * 40 * sizeof(float));
  bf16* Wt1 = (bf16*)alloc((size_t)512 * 512 * sizeof(bf16));
  bf16* Wt2 = (bf16*)alloc((size_t)512 * 512 * sizeof(bf16));
  bf16* Wt3 = (bf16*)alloc((size_t)128 * 512 * sizeof(bf16));
  int* eoff = (int*)alloc((N_EDGES_C + 1) * sizeof(int));
  int* voff = (int*)alloc((N_NODES + 1) * sizeof(int));
  int* evtx = (int*)alloc((size_t)NNZ_C * sizeof(int));
  int* vedg = (int*)alloc((size_t)NNZ_C * sizeof(int));
  // counters in ONE contiguous region: cntE | cntV | curE | curV
  int* cnts = (int*)alloc((size_t)(2 * (N_EDGES_C + N_NODES)) * sizeof(int));
  int* cntE = cnts;
  int* cntV = cnts + N_EDGES_C;
  int* curE = cnts + N_EDGES_C + N_NODES;
  int* curV = cnts + 2 * N_EDGES_C + N_NODES;
  int* partE = (int*)alloc(64 * sizeof(int));
  int* partV = (int*)alloc(64 * sizeof(int));

  hipMemsetAsync(cnts, 0, (size_t)(2 * (N_EDGES_C + N_NODES)) * sizeof(int), stream);

  prep_kernel<<<2304, 256, 0, stream>>>(W1, W2, Wout, Wt1, Wt2, Wt3);

  hist_kernel<<<(NNZ_C + 255) / 256, 256, 0, stream>>>(vertex, edges, cntV, cntE, NNZ_C);

  const int nbE = (N_EDGES_C + SCHUNK - 1) / SCHUNK;  // 13
  const int nbV = (N_NODES + SCHUNK - 1) / SCHUNK;    // 25
  scan_part2<<<nbE + nbV, 256, 0, stream>>>(cntE, cntV, partE, partV, nbE);
  scan_mid2<<<1, 128, 0, stream>>>(partE, partV, eoff, voff, nbE, nbV);
  scan_final2<<<nbE + nbV, 256, 0, stream>>>(cntE, cntV, partE, partV, eoff, voff, nbE);

  scatter_kernel<<<(NNZ_C + 255) / 256, 256, 0, stream>>>(vertex, edges, eoff, voff,
                                                          curE, curV, evtx, vedg, NNZ_C);

  const int MB = (N_NODES + 127) / 128;

  // ---- layer 1 (fused f32->bf16 convert in GEMM A-staging) ----
  {
    dim3 g(4, MB);
    gemm_af32_kernel<<<g, 256, 0, stream>>>(X, Wt1, Yb, N_NODES, 512, 512);
  }
  edge_agg_w<<<(N_EDGES_C + 3) / 4, 256, 0, stream>>>(Yb, eoff, evtx, degE, XeB, N_EDGES_C);
  vtx_agg_w<<<(N_NODES + 3) / 4, 256, 0, stream>>>(XeB, voff, vedg, degV, Xb, N_NODES);

  // ---- layer 2 ----
  {
    dim3 g(4, MB);
    gemm_bf16_kernel<1><<<g, 256, 0, stream>>>(Xb, Wt2, nullptr, Yb, N_NODES, 512, 512, 512);
  }
  edge_agg_w<<<(N_EDGES_C + 3) / 4, 256, 0, stream>>>(Yb, eoff, evtx, degE, XeB, N_EDGES_C);
  vtx_agg_w<<<(N_NODES + 3) / 4, 256, 0, stream>>>(XeB, voff, vedg, degV, Xb, N_NODES);

  // ---- layer 3 (C=40) ----
  {
    dim3 g(1, MB);
    gemm_bf16_kernel<0><<<g, 256, 0, stream>>>(Xb, Wt3, Y40, nullptr, N_NODES, 512, 40, 40);
  }
  edge_agg40_w<<<(N_EDGES_C + 3) / 4, 256, 0, stream>>>(Y40, eoff, evtx, degE, Xe40, N_EDGES_C);
  vtx_agg_lsm<<<(N_NODES + 3) / 4, 256, 0, stream>>>(Xe40, voff, vedg, degV, out, N_NODES);
}

// Round 9
// 511.657 us; speedup vs baseline: 1.0627x; 1.0143x over previous
//
#include <hip/hip_runtime.h>

#define N_NODES 50000
#define N_EDGES_C 25000
#define NNZ_C 400000
#define SCHUNK 2048

typedef __bf16 bf16;
typedef __bf16 bf16x8 __attribute__((ext_vector_type(8)));
typedef __bf16 bf16x4 __attribute__((ext_vector_type(4)));
typedef float f32x4 __attribute__((ext_vector_type(4)));

typedef __attribute__((address_space(1))) const void as1_cvoid;
typedef __attribute__((address_space(3))) void as3_void;

__device__ __forceinline__ void gload_lds16(const bf16* g, bf16* l) {
  __builtin_amdgcn_global_load_lds((as1_cvoid*)g, (as3_void*)l, 16, 0, 0);
}

// ---------------- CSR build ----------------
__global__ void hist_kernel(const int* __restrict__ vtx, const int* __restrict__ edg,
                            int* __restrict__ cntV, int* __restrict__ cntE, int nnz) {
  int i = blockIdx.x * blockDim.x + threadIdx.x;
  if (i < nnz) {
    atomicAdd(&cntV[vtx[i]], 1);
    atomicAdd(&cntE[edg[i]], 1);
  }
}

__global__ void scan_part2(const int* __restrict__ cntE, const int* __restrict__ cntV,
                           int* __restrict__ partE, int* __restrict__ partV,
                           int nbE) {
  __shared__ int red[256];
  const int t = threadIdx.x;
  const int isV = (blockIdx.x >= nbE);
  const int b = isV ? (blockIdx.x - nbE) : blockIdx.x;
  const int* cnt = isV ? cntV : cntE;
  const int n = isV ? N_NODES : N_EDGES_C;
  const int base = b * SCHUNK + t * 8;
  int s = 0;
#pragma unroll
  for (int q = 0; q < 8; ++q) {
    int i = base + q;
    if (i < n) s += cnt[i];
  }
  red[t] = s;
  __syncthreads();
  for (int d = 128; d > 0; d >>= 1) {
    if (t < d) red[t] += red[t + d];
    __syncthreads();
  }
  if (t == 0) (isV ? partV : partE)[b] = red[0];
}

__global__ void scan_mid2(int* __restrict__ partE, int* __restrict__ partV,
                          int* __restrict__ eoff, int* __restrict__ voff,
                          int nbE, int nbV) {
  const int wv = threadIdx.x >> 6;
  const int lane = threadIdx.x & 63;
  int* part = wv ? partV : partE;
  int* off = wv ? voff : eoff;
  const int np = wv ? nbV : nbE;
  const int n = wv ? N_NODES : N_EDGES_C;
  int orig = (lane < np) ? part[lane] : 0;
  int v = orig;
  for (int o = 1; o < 64; o <<= 1) {
    int x = __shfl_up(v, o);
    if (lane >= o) v += x;
  }
  if (lane < np) part[lane] = v - orig;
  if (lane == 63) off[n] = v;
}

__global__ void scan_final2(const int* __restrict__ cntE, const int* __restrict__ cntV,
                            const int* __restrict__ partE, const int* __restrict__ partV,
                            int* __restrict__ eoff, int* __restrict__ voff, int nbE) {
  __shared__ int tsum[256];
  const int t = threadIdx.x;
  const int isV = (blockIdx.x >= nbE);
  const int b = isV ? (blockIdx.x - nbE) : blockIdx.x;
  const int* cnt = isV ? cntV : cntE;
  const int* part = isV ? partV : partE;
  int* off = isV ? voff : eoff;
  const int n = isV ? N_NODES : N_EDGES_C;
  const int base = b * SCHUNK + t * 8;
  int loc[8];
  int s = 0;
#pragma unroll
  for (int q = 0; q < 8; ++q) {
    int i = base + q;
    loc[q] = (i < n) ? cnt[i] : 0;
    s += loc[q];
  }
  tsum[t] = s;
  __syncthreads();
  for (int d = 1; d < 256; d <<= 1) {
    int x = (t >= d) ? tsum[t - d] : 0;
    __syncthreads();
    tsum[t] += x;
    __syncthreads();
  }
  int run = part[b] + ((t > 0) ? tsum[t - 1] : 0);
#pragma unroll
  for (int q = 0; q < 8; ++q) {
    int i = base + q;
    if (i < n) off[i] = run;
    run += loc[q];
  }
}

__global__ void scatter_kernel(const int* __restrict__ vtx, const int* __restrict__ edg,
                               const int* __restrict__ eoff, const int* __restrict__ voff,
                               int* __restrict__ curE, int* __restrict__ curV,
                               int* __restrict__ evtx, int* __restrict__ vedg, int nnz) {
  int i = blockIdx.x * blockDim.x + threadIdx.x;
  if (i < nnz) {
    int e = edg[i], v = vtx[i];
    int p = atomicAdd(&curE[e], 1);
    evtx[eoff[e] + p] = v;
    int q = atomicAdd(&curV[v], 1);
    vedg[voff[v] + q] = e;
  }
}

// ---------------- prep: weight transposes + X f32->bf16, one launch ----------------
__global__ void prep_conv(const float* __restrict__ W1, const float* __restrict__ W2,
                          const float* __restrict__ Wout, const float* __restrict__ X,
                          bf16* __restrict__ Wt1, bf16* __restrict__ Wt2,
                          bf16* __restrict__ Wt3, bf16* __restrict__ Xb) {
  const int b = blockIdx.x;
  const int t = threadIdx.x;
  if (b < 1024) {  // W1: 512x512 transpose
    int idx = b * 256 + t;
    int n = idx >> 9, k = idx & 511;
    Wt1[idx] = (bf16)W1[(size_t)k * 512 + n];
  } else if (b < 2048) {  // W2
    int idx = (b - 1024) * 256 + t;
    int n = idx >> 9, k = idx & 511;
    Wt2[idx] = (bf16)W2[(size_t)k * 512 + n];
  } else if (b < 2304) {  // Wout: 128 rows x 512, N=40 pad
    int idx = (b - 2048) * 256 + t;
    int n = idx >> 9, k = idx & 511;
    Wt3[idx] = (n < 40) ? (bf16)Wout[(size_t)k * 40 + n] : (bf16)0.0f;
  } else {  // X convert: 8 f32 -> bf16x8 per thread
    size_t i = ((size_t)(b - 2304) * 256 + t) * 8;
    float4 v0 = *(const float4*)(X + i);
    float4 v1 = *(const float4*)(X + i + 4);
    bf16x8 o;
    o[0] = (bf16)v0.x; o[1] = (bf16)v0.y; o[2] = (bf16)v0.z; o[3] = (bf16)v0.w;
    o[4] = (bf16)v1.x; o[5] = (bf16)v1.y; o[6] = (bf16)v1.z; o[7] = (bf16)v1.w;
    *(bf16x8*)(Xb + i) = o;
  }
}

// ---------------- GEMM (bf16 A): BK=64, swizzled LDS, dbuf counted-vmcnt ----------------
// grid(NB, MB): x = n-block (consecutive blocks share the A tile -> L2/L3 reuse)
template <int BF16OUT>
__global__ __launch_bounds__(256) void gemm_bf16_kernel(
    const bf16* __restrict__ A, const bf16* __restrict__ B,
    float* __restrict__ Cf, bf16* __restrict__ Cb, int M, int K, int ldC, int Nstore) {
  __shared__ bf16 Al[2][128][64];
  __shared__ bf16 Bl[2][128][64];
  const int t = threadIdx.x;
  const int n0 = blockIdx.x * 128;
  const int m0 = blockIdx.y * 128;
  const int w = t >> 6, lane = t & 63;
  const int wr = w >> 1, wc = w & 1;
  const int lr = lane & 15;
  const int ls = lane >> 4;

  f32x4 acc[4][4];
#pragma unroll
  for (int m = 0; m < 4; ++m)
#pragma unroll
    for (int n = 0; n < 4; ++n) acc[m][n] = (f32x4){0.f, 0.f, 0.f, 0.f};

  const int srow8 = lane >> 3;
  const int scol = ((lane & 7) ^ srow8) << 3;

  const bf16* Abase = A + (size_t)m0 * K;
  const bf16* Bbase = B + (size_t)n0 * K;

#define STAGE(tile, bsel)                                                        \
  {                                                                              \
    const int kk_ = (tile) * 64;                                                 \
    _Pragma("unroll")                                                            \
    for (int q = 0; q < 4; ++q) {                                                \
      const int row = w * 32 + q * 8 + srow8;                                    \
      gload_lds16(Abase + (size_t)row * K + kk_ + scol, &Al[bsel][w*32+q*8][0]); \
      gload_lds16(Bbase + (size_t)row * K + kk_ + scol, &Bl[bsel][w*32+q*8][0]); \
    }                                                                            \
  }

  const int NT = K >> 6;
  STAGE(0, 0);
  for (int tt = 0; tt < NT; ++tt) {
    const int cur = tt & 1;
    if (tt + 1 < NT) {
      STAGE(tt + 1, cur ^ 1);
      asm volatile("s_waitcnt vmcnt(8)" ::: "memory");
    } else {
      asm volatile("s_waitcnt vmcnt(0)" ::: "memory");
    }
    __builtin_amdgcn_s_barrier();
    __builtin_amdgcn_s_setprio(1);
#pragma unroll
    for (int ks = 0; ks < 2; ++ks) {
      bf16x8 af[4], bfr[4];
#pragma unroll
      for (int m = 0; m < 4; ++m) {
        const int R = wr * 64 + m * 16 + lr;
        af[m] = *(const bf16x8*)(&Al[cur][R][((ks * 4 + ls) ^ (lr & 7)) << 3]);
      }
#pragma unroll
      for (int n = 0; n < 4; ++n) {
        const int R = wc * 64 + n * 16 + lr;
        bfr[n] = *(const bf16x8*)(&Bl[cur][R][((ks * 4 + ls) ^ (lr & 7)) << 3]);
      }
#pragma unroll
      for (int m = 0; m < 4; ++m)
#pragma unroll
        for (int n = 0; n < 4; ++n)
          acc[m][n] = __builtin_amdgcn_mfma_f32_16x16x32_bf16(af[m], bfr[n], acc[m][n], 0, 0, 0);
    }
    __builtin_amdgcn_s_setprio(0);
    __builtin_amdgcn_s_barrier();
  }
#undef STAGE

  const int cr = (lane >> 4) << 2;  // C/D: col = lane&15, row = (lane>>4)*4 + i
  const int cc = lane & 15;
#pragma unroll
  for (int m = 0; m < 4; ++m) {
#pragma unroll
    for (int n = 0; n < 4; ++n) {
      int gc = n0 + wc * 64 + n * 16 + cc;
      if (gc >= Nstore) continue;
#pragma unroll
      for (int i = 0; i < 4; ++i) {
        int gr = m0 + wr * 64 + m * 16 + cr + i;
        if (gr < M) {
          if (BF16OUT) Cb[(size_t)gr * ldC + gc] = (bf16)acc[m][n][i];
          else         Cf[(size_t)gr * ldC + gc] = acc[m][n][i];
        }
      }
    }
  }
}

// ---------------- wave-per-edge aggregation (bf16, C=512), unroll-2 ----------------
__global__ __launch_bounds__(256) void edge_agg_w(
    const bf16* __restrict__ Y, const int* __restrict__ eoff, const int* __restrict__ evtx,
    const float* __restrict__ degE, bf16* __restrict__ Xe, int nE) {
  const int wv = (blockIdx.x * 256 + threadIdx.x) >> 6;
  if (wv >= nE) return;
  const int lane = threadIdx.x & 63;
  const int beg = eoff[wv], end = eoff[wv + 1];
  const int cnt = end - beg;
  const float scale = (cnt > 0) ? degE[wv] / (float)cnt : 0.f;
  float acc[8] = {0.f, 0.f, 0.f, 0.f, 0.f, 0.f, 0.f, 0.f};
  for (int base = beg; base < end; base += 64) {
    const int nb = min(64, end - base);
    int myidx = (lane < nb) ? evtx[base + lane] : 0;
    int j = 0;
    for (; j + 1 < nb; j += 2) {
      const int i0 = __shfl(myidx, j);
      const int i1 = __shfl(myidx, j + 1);
      bf16x8 v0 = *(const bf16x8*)(Y + (size_t)i0 * 512 + lane * 8);
      bf16x8 v1 = *(const bf16x8*)(Y + (size_t)i1 * 512 + lane * 8);
#pragma unroll
      for (int q = 0; q < 8; ++q) acc[q] += (float)v0[q] + (float)v1[q];
    }
    if (j < nb) {
      const int i0 = __shfl(myidx, j);
      bf16x8 v0 = *(const bf16x8*)(Y + (size_t)i0 * 512 + lane * 8);
#pragma unroll
      for (int q = 0; q < 8; ++q) acc[q] += (float)v0[q];
    }
  }
  bf16x8 o;
#pragma unroll
  for (int q = 0; q < 8; ++q) o[q] = (bf16)(acc[q] * scale);
  *(bf16x8*)(Xe + (size_t)wv * 512 + lane * 8) = o;
}

// ---------------- wave-per-vertex aggregation (bf16, relu, C=512), unroll-2 ----------------
__global__ __launch_bounds__(256) void vtx_agg_w(
    const bf16* __restrict__ Xe, const int* __restrict__ voff, const int* __restrict__ vedg,
    const float* __restrict__ degV, bf16* __restrict__ outB, int nV) {
  const int wv = (blockIdx.x * 256 + threadIdx.x) >> 6;
  if (wv >= nV) return;
  const int lane = threadIdx.x & 63;
  const int beg = voff[wv], end = voff[wv + 1];
  const float dv = degV[wv];
  float acc[8] = {0.f, 0.f, 0.f, 0.f, 0.f, 0.f, 0.f, 0.f};
  for (int base = beg; base < end; base += 64) {
    const int nb = min(64, end - base);
    int myidx = (lane < nb) ? vedg[base + lane] : 0;
    int j = 0;
    for (; j + 1 < nb; j += 2) {
      const int i0 = __shfl(myidx, j);
      const int i1 = __shfl(myidx, j + 1);
      bf16x8 v0 = *(const bf16x8*)(Xe + (size_t)i0 * 512 + lane * 8);
      bf16x8 v1 = *(const bf16x8*)(Xe + (size_t)i1 * 512 + lane * 8);
#pragma unroll
      for (int q = 0; q < 8; ++q) acc[q] += (float)v0[q] + (float)v1[q];
    }
    if (j < nb) {
      const int i0 = __shfl(myidx, j);
      bf16x8 v0 = *(const bf16x8*)(Xe + (size_t)i0 * 512 + lane * 8);
#pragma unroll
      for (int q = 0; q < 8; ++q) acc[q] += (float)v0[q];
    }
  }
  bf16x8 o;
#pragma unroll
  for (int q = 0; q < 8; ++q) o[q] = (bf16)fmaxf(acc[q] * dv, 0.f);
  *(bf16x8*)(outB + (size_t)wv * 512 + lane * 8) = o;
}

// ---------------- wave-per-edge aggregation bf16 (layer 3, C=40) ----------------
__global__ __launch_bounds__(256) void edge_agg40_w(
    const bf16* __restrict__ Y, const int* __restrict__ eoff, const int* __restrict__ evtx,
    const float* __restrict__ degE, bf16* __restrict__ Xe, int nE) {
  const int wv = (blockIdx.x * 256 + threadIdx.x) >> 6;
  if (wv >= nE) return;
  const int lane = threadIdx.x & 63;
  const int beg = eoff[wv], end = eoff[wv + 1];
  const int cnt = end - beg;
  const float scale = (cnt > 0) ? degE[wv] / (float)cnt : 0.f;
  float a0 = 0.f;
  for (int base = beg; base < end; base += 64) {
    const int nb = min(64, end - base);
    int myidx = (lane < nb) ? evtx[base + lane] : 0;
    int j = 0;
    for (; j + 3 < nb; j += 4) {
      const int i0 = __shfl(myidx, j);
      const int i1 = __shfl(myidx, j + 1);
      const int i2 = __shfl(myidx, j + 2);
      const int i3 = __shfl(myidx, j + 3);
      if (lane < 40) {
        float x0 = (float)Y[(size_t)i0 * 40 + lane];
        float x1 = (float)Y[(size_t)i1 * 40 + lane];
        float x2 = (float)Y[(size_t)i2 * 40 + lane];
        float x3 = (float)Y[(size_t)i3 * 40 + lane];
        a0 += (x0 + x1) + (x2 + x3);
      }
    }
    for (; j < nb; ++j) {
      const int i0 = __shfl(myidx, j);
      if (lane < 40) a0 += (float)Y[(size_t)i0 * 40 + lane];
    }
  }
  if (lane < 40) Xe[(size_t)wv * 40 + lane] = (bf16)(a0 * scale);
}

// ---------------- final vertex aggregation + log_softmax (C=40) ----------------
__global__ __launch_bounds__(256) void vtx_agg_lsm(
    const bf16* __restrict__ Xe, const int* __restrict__ voff, const int* __restrict__ vedg,
    const float* __restrict__ degV, float* __restrict__ out, int nV) {
  const int wv = (blockIdx.x * 256 + threadIdx.x) >> 6;
  if (wv >= nV) return;
  const int lane = threadIdx.x & 63;
  const int beg = voff[wv], end = voff[wv + 1];
  const float dv = degV[wv];
  float a0 = 0.f;
  for (int base = beg; base < end; base += 64) {
    const int nb = min(64, end - base);
    int myidx = (lane < nb) ? vedg[base + lane] : 0;
    int j = 0;
    for (; j + 3 < nb; j += 4) {
      const int i0 = __shfl(myidx, j);
      const int i1 = __shfl(myidx, j + 1);
      const int i2 = __shfl(myidx, j + 2);
      const int i3 = __shfl(myidx, j + 3);
      if (lane < 40) {
        float x0 = (float)Xe[(size_t)i0 * 40 + lane];
        float x1 = (float)Xe[(size_t)i1 * 40 + lane];
        float x2 = (float)Xe[(size_t)i2 * 40 + lane];
        float x3 = (float)Xe[(size_t)i3 * 40 + lane];
        a0 += (x0 + x1) + (x2 + x3);
      }
    }
    for (; j < nb; ++j) {
      const int i0 = __shfl(myidx, j);
      if (lane < 40) a0 += (float)Xe[(size_t)i0 * 40 + lane];
    }
  }
  a0 *= dv;
  float val = (lane < 40) ? a0 : -3.4e38f;
  float m = val;
#pragma unroll
  for (int o = 32; o > 0; o >>= 1) m = fmaxf(m, __shfl_xor(m, o));
  float ex = (lane < 40) ? expf(val - m) : 0.f;
  float s = ex;
#pragma unroll
  for (int o = 32; o > 0; o >>= 1) s += __shfl_xor(s, o);
  float ls = logf(s);
  if (lane < 40) out[(size_t)wv * 40 + lane] = val - m - ls;
}

extern "C" void kernel_launch(void* const* d_in, const int* in_sizes, int n_in,
                              void* d_out, int out_size, void* d_ws, size_t ws_size,
                              hipStream_t stream) {
  (void)in_sizes; (void)n_in; (void)out_size; (void)ws_size;
  const float* X = (const float*)d_in[0];
  const int* vertex = (const int*)d_in[1];
  const int* edges = (const int*)d_in[2];
  const float* W1 = (const float*)d_in[3];
  const float* W2 = (const float*)d_in[4];
  const float* Wout = (const float*)d_in[5];
  const float* degE = (const float*)d_in[6];
  const float* degV = (const float*)d_in[7];
  float* out = (float*)d_out;

  char* ws = (char*)d_ws;
  size_t off = 0;
  auto alloc = [&](size_t bytes) -> void* {
    void* p = ws + off;
    off += (bytes + 255) & ~(size_t)255;
    return p;
  };
  bf16* Xb  = (bf16*)alloc((size_t)N_NODES * 512 * sizeof(bf16));
  bf16* Yb  = (bf16*)alloc((size_t)N_NODES * 512 * sizeof(bf16));
  bf16* XeB = (bf16*)alloc((size_t)N_EDGES_C * 512 * sizeof(bf16));
  bf16* Y40b  = (bf16*)alloc((size_t)N_NODES * 40 * sizeof(bf16));
  bf16* Xe40b = (bf16*)alloc((size_t)N_EDGES_C * 40 * sizeof(bf16));
  bf16* Wt1 = (bf16*)alloc((size_t)512 * 512 * sizeof(bf16));
  bf16* Wt2 = (bf16*)alloc((size_t)512 * 512 * sizeof(bf16));
  bf16* Wt3 = (bf16*)alloc((size_t)128 * 512 * sizeof(bf16));
  int* eoff = (int*)alloc((N_EDGES_C + 1) * sizeof(int));
  int* voff = (int*)alloc((N_NODES + 1) * sizeof(int));
  int* evtx = (int*)alloc((size_t)NNZ_C * sizeof(int));
  int* vedg = (int*)alloc((size_t)NNZ_C * sizeof(int));
  int* cnts = (int*)alloc((size_t)(2 * (N_EDGES_C + N_NODES)) * sizeof(int));
  int* cntE = cnts;
  int* cntV = cnts + N_EDGES_C;
  int* curE = cnts + N_EDGES_C + N_NODES;
  int* curV = cnts + 2 * N_EDGES_C + N_NODES;
  int* partE = (int*)alloc(64 * sizeof(int));
  int* partV = (int*)alloc(64 * sizeof(int));

  hipMemsetAsync(cnts, 0, (size_t)(2 * (N_EDGES_C + N_NODES)) * sizeof(int), stream);

  // prep (weights + X convert) — independent of CSR chain, one launch
  // grid: 2304 weight blocks + 12500 X-convert blocks
  prep_conv<<<2304 + 12500, 256, 0, stream>>>(W1, W2, Wout, X, Wt1, Wt2, Wt3, Xb);

  hist_kernel<<<(NNZ_C + 255) / 256, 256, 0, stream>>>(vertex, edges, cntV, cntE, NNZ_C);

  const int nbE = (N_EDGES_C + SCHUNK - 1) / SCHUNK;  // 13
  const int nbV = (N_NODES + SCHUNK - 1) / SCHUNK;    // 25
  scan_part2<<<nbE + nbV, 256, 0, stream>>>(cntE, cntV, partE, partV, nbE);
  scan_mid2<<<1, 128, 0, stream>>>(partE, partV, eoff, voff, nbE, nbV);
  scan_final2<<<nbE + nbV, 256, 0, stream>>>(cntE, cntV, partE, partV, eoff, voff, nbE);

  scatter_kernel<<<(NNZ_C + 255) / 256, 256, 0, stream>>>(vertex, edges, eoff, voff,
                                                          curE, curV, evtx, vedg, NNZ_C);

  const int MB = (N_NODES + 127) / 128;

  // ---- layer 1 ----
  {
    dim3 g(4, MB);
    gemm_bf16_kernel<1><<<g, 256, 0, stream>>>(Xb, Wt1, nullptr, Yb, N_NODES, 512, 512, 512);
  }
  edge_agg_w<<<(N_EDGES_C + 3) / 4, 256, 0, stream>>>(Yb, eoff, evtx, degE, XeB, N_EDGES_C);
  vtx_agg_w<<<(N_NODES + 3) / 4, 256, 0, stream>>>(XeB, voff, vedg, degV, Xb, N_NODES);

  // ---- layer 2 ----
  {
    dim3 g(4, MB);
    gemm_bf16_kernel<1><<<g, 256, 0, stream>>>(Xb, Wt2, nullptr, Yb, N_NODES, 512, 512, 512);
  }
  edge_agg_w<<<(N_EDGES_C + 3) / 4, 256, 0, stream>>>(Yb, eoff, evtx, degE, XeB, N_EDGES_C);
  vtx_agg_w<<<(N_NODES + 3) / 4, 256, 0, stream>>>(XeB, voff, vedg, degV, Xb, N_NODES);

  // ---- layer 3 (C=40, bf16 end-to-end until log_softmax) ----
  {
    dim3 g(1, MB);
    gemm_bf16_kernel<1><<<g, 256, 0, stream>>>(Xb, Wt3, nullptr, Y40b, N_NODES, 512, 40, 40);
  }
  edge_agg40_w<<<(N_EDGES_C + 3) / 4, 256, 0, stream>>>(Y40b, eoff, evtx, degE, Xe40b, N_EDGES_C);
  vtx_agg_lsm<<<(N_NODES + 3) / 4, 256, 0, stream>>>(Xe40b, voff, vedg, degV, out, N_NODES);
}

// Round 11
// 498.754 us; speedup vs baseline: 1.0902x; 1.0259x over previous
//
#include <hip/hip_runtime.h>

#define N_NODES 50000
#define N_EDGES_C 25000
#define NNZ_C 400000
#define SCHUNK 2048

typedef __bf16 bf16;
typedef __bf16 bf16x8 __attribute__((ext_vector_type(8)));
typedef __bf16 bf16x4 __attribute__((ext_vector_type(4)));
typedef float f32x4 __attribute__((ext_vector_type(4)));

typedef __attribute__((address_space(1))) const void as1_cvoid;
typedef __attribute__((address_space(3))) void as3_void;

__device__ __forceinline__ void gload_lds16(const bf16* g, bf16* l) {
  __builtin_amdgcn_global_load_lds((as1_cvoid*)g, (as3_void*)l, 16, 0, 0);
}

// ---------------- CSR build ----------------
__global__ void hist_kernel(const int* __restrict__ vtx, const int* __restrict__ edg,
                            int* __restrict__ cntV, int* __restrict__ cntE, int nnz) {
  int i = blockIdx.x * blockDim.x + threadIdx.x;
  if (i < nnz) {
    atomicAdd(&cntV[vtx[i]], 1);
    atomicAdd(&cntE[edg[i]], 1);
  }
}

__global__ void scan_part2(const int* __restrict__ cntE, const int* __restrict__ cntV,
                           int* __restrict__ partE, int* __restrict__ partV,
                           int nbE) {
  __shared__ int red[256];
  const int t = threadIdx.x;
  const int isV = (blockIdx.x >= nbE);
  const int b = isV ? (blockIdx.x - nbE) : blockIdx.x;
  const int* cnt = isV ? cntV : cntE;
  const int n = isV ? N_NODES : N_EDGES_C;
  const int base = b * SCHUNK + t * 8;
  int s = 0;
#pragma unroll
  for (int q = 0; q < 8; ++q) {
    int i = base + q;
    if (i < n) s += cnt[i];
  }
  red[t] = s;
  __syncthreads();
  for (int d = 128; d > 0; d >>= 1) {
    if (t < d) red[t] += red[t + d];
    __syncthreads();
  }
  if (t == 0) (isV ? partV : partE)[b] = red[0];
}

__global__ void scan_mid2(int* __restrict__ partE, int* __restrict__ partV,
                          int* __restrict__ eoff, int* __restrict__ voff,
                          int nbE, int nbV) {
  const int wv = threadIdx.x >> 6;
  const int lane = threadIdx.x & 63;
  int* part = wv ? partV : partE;
  int* off = wv ? voff : eoff;
  const int np = wv ? nbV : nbE;
  const int n = wv ? N_NODES : N_EDGES_C;
  int orig = (lane < np) ? part[lane] : 0;
  int v = orig;
  for (int o = 1; o < 64; o <<= 1) {
    int x = __shfl_up(v, o);
    if (lane >= o) v += x;
  }
  if (lane < np) part[lane] = v - orig;
  if (lane == 63) off[n] = v;
}

__global__ void scan_final2(const int* __restrict__ cntE, const int* __restrict__ cntV,
                            const int* __restrict__ partE, const int* __restrict__ partV,
                            int* __restrict__ eoff, int* __restrict__ voff, int nbE) {
  __shared__ int tsum[256];
  const int t = threadIdx.x;
  const int isV = (blockIdx.x >= nbE);
  const int b = isV ? (blockIdx.x - nbE) : blockIdx.x;
  const int* cnt = isV ? cntV : cntE;
  const int* part = isV ? partV : partE;
  int* off = isV ? voff : eoff;
  const int n = isV ? N_NODES : N_EDGES_C;
  const int base = b * SCHUNK + t * 8;
  int loc[8];
  int s = 0;
#pragma unroll
  for (int q = 0; q < 8; ++q) {
    int i = base + q;
    loc[q] = (i < n) ? cnt[i] : 0;
    s += loc[q];
  }
  tsum[t] = s;
  __syncthreads();
  for (int d = 1; d < 256; d <<= 1) {
    int x = (t >= d) ? tsum[t - d] : 0;
    __syncthreads();
    tsum[t] += x;
    __syncthreads();
  }
  int run = part[b] + ((t > 0) ? tsum[t - 1] : 0);
#pragma unroll
  for (int q = 0; q < 8; ++q) {
    int i = base + q;
    if (i < n) off[i] = run;
    run += loc[q];
  }
}

__global__ void scatter_kernel(const int* __restrict__ vtx, const int* __restrict__ edg,
                               const int* __restrict__ eoff, const int* __restrict__ voff,
                               int* __restrict__ curE, int* __restrict__ curV,
                               int* __restrict__ evtx, int* __restrict__ vedg, int nnz) {
  int i = blockIdx.x * blockDim.x + threadIdx.x;
  if (i < nnz) {
    int e = edg[i], v = vtx[i];
    int p = atomicAdd(&curE[e], 1);
    evtx[eoff[e] + p] = v;
    int q = atomicAdd(&curV[v], 1);
    vedg[voff[v] + q] = e;
  }
}

// ---------------- prep: weight transposes + X f32->bf16, one launch ----------------
__global__ void prep_conv(const float* __restrict__ W1, const float* __restrict__ W2,
                          const float* __restrict__ Wout, const float* __restrict__ X,
                          bf16* __restrict__ Wt1, bf16* __restrict__ Wt2,
                          bf16* __restrict__ Wt3, bf16* __restrict__ Xb) {
  const int b = blockIdx.x;
  const int t = threadIdx.x;
  if (b < 1024) {
    int idx = b * 256 + t;
    int n = idx >> 9, k = idx & 511;
    Wt1[idx] = (bf16)W1[(size_t)k * 512 + n];
  } else if (b < 2048) {
    int idx = (b - 1024) * 256 + t;
    int n = idx >> 9, k = idx & 511;
    Wt2[idx] = (bf16)W2[(size_t)k * 512 + n];
  } else if (b < 2304) {
    int idx = (b - 2048) * 256 + t;
    int n = idx >> 9, k = idx & 511;
    Wt3[idx] = (n < 40) ? (bf16)Wout[(size_t)k * 40 + n] : (bf16)0.0f;
  } else {
    size_t i = ((size_t)(b - 2304) * 256 + t) * 8;
    float4 v0 = *(const float4*)(X + i);
    float4 v1 = *(const float4*)(X + i + 4);
    bf16x8 o;
    o[0] = (bf16)v0.x; o[1] = (bf16)v0.y; o[2] = (bf16)v0.z; o[3] = (bf16)v0.w;
    o[4] = (bf16)v1.x; o[5] = (bf16)v1.y; o[6] = (bf16)v1.z; o[7] = (bf16)v1.w;
    *(bf16x8*)(Xb + i) = o;
  }
}

// ---------------- GEMM: BK=64, swizzled LDS, dbuf counted-vmcnt, XCD-chunked 1-D grid ----------------
// Each gload_lds16 stages 8 rows (64 lanes x 16B = 1024B = 8 x 128B rows), so a
// T-row tile needs T/32 issues per wave (4 waves).  A: 4/wave.  B: TN/32/wave.
// XCD chunk swizzle: wid = (bid%8)*cpx + bid/8 (grid multiple of 8) -> each XCD owns
// contiguous wids = whole sibling groups -> A row-panel enters each L2 once.
template <int TN>
__global__ __launch_bounds__(256) void gemm_bf16_kernel(
    const bf16* __restrict__ A, const bf16* __restrict__ B,
    bf16* __restrict__ Cb, int M, int K, int ldC, int Nstore) {
  __shared__ bf16 Al[2][128][64];
  __shared__ bf16 Bl[2][TN][64];
  const int bid = blockIdx.x;
  const int cpx = gridDim.x >> 3;
  const int wid = (bid & 7) * cpx + (bid >> 3);
  const int MBLK = (M + 127) >> 7;
  int mIdx, nIdx;
  if (TN == 128) { mIdx = wid >> 2; nIdx = wid & 3; }
  else           { mIdx = wid;      nIdx = 0; }
  if (mIdx >= MBLK) return;
  const int m0 = mIdx * 128;
  const int n0 = nIdx * TN;

  const int t = threadIdx.x;
  const int w = t >> 6, lane = t & 63;
  // wave tile: TN=128 -> 2x2 (64x64 each); TN=64 -> 4x1 (32x64 each)
  const int rb = (TN == 128) ? ((w >> 1) * 64) : (w * 32);
  const int cb = (TN == 128) ? ((w & 1) * 64) : 0;
  const int MF = (TN == 128) ? 4 : 2;
  const int lr = lane & 15;
  const int ls = lane >> 4;

  f32x4 acc[(TN == 128) ? 4 : 2][4];
#pragma unroll
  for (int m = 0; m < MF; ++m)
#pragma unroll
    for (int n = 0; n < 4; ++n) acc[m][n] = (f32x4){0.f, 0.f, 0.f, 0.f};

  const int srow8 = lane >> 3;
  const int scol = ((lane & 7) ^ srow8) << 3;

  const bf16* Abase = A + (size_t)m0 * K;
  const bf16* Bbase = B + (size_t)n0 * K;

#define STAGE(tile, bsel)                                                          \
  {                                                                                \
    const int kk_ = (tile) * 64;                                                   \
    _Pragma("unroll")                                                              \
    for (int q = 0; q < 4; ++q) {                                                  \
      const int row = w * 32 + q * 8 + srow8;                                      \
      gload_lds16(Abase + (size_t)row * K + kk_ + scol, &Al[bsel][w*32+q*8][0]);   \
    }                                                                              \
    _Pragma("unroll")                                                              \
    for (int q = 0; q < TN / 32; ++q) {                                            \
      const int row = w * (TN / 4) + q * 8 + srow8;                                \
      gload_lds16(Bbase + (size_t)row * K + kk_ + scol,                            \
                  &Bl[bsel][w * (TN / 4) + q * 8][0]);                             \
    }                                                                              \
  }

  const int NT = K >> 6;
  STAGE(0, 0);
  for (int tt = 0; tt < NT; ++tt) {
    const int cur = tt & 1;
    if (tt + 1 < NT) {
      STAGE(tt + 1, cur ^ 1);
      if (TN == 128) asm volatile("s_waitcnt vmcnt(8)" ::: "memory");
      else           asm volatile("s_waitcnt vmcnt(6)" ::: "memory");
    } else {
      asm volatile("s_waitcnt vmcnt(0)" ::: "memory");
    }
    __builtin_amdgcn_s_barrier();
    __builtin_amdgcn_s_setprio(1);
#pragma unroll
    for (int ks = 0; ks < 2; ++ks) {
      bf16x8 af[(TN == 128) ? 4 : 2], bfr[4];
#pragma unroll
      for (int m = 0; m < MF; ++m) {
        const int R = rb + m * 16 + lr;
        af[m] = *(const bf16x8*)(&Al[cur][R][((ks * 4 + ls) ^ (lr & 7)) << 3]);
      }
#pragma unroll
      for (int n = 0; n < 4; ++n) {
        const int R = cb + n * 16 + lr;
        bfr[n] = *(const bf16x8*)(&Bl[cur][R][((ks * 4 + ls) ^ (lr & 7)) << 3]);
      }
#pragma unroll
      for (int m = 0; m < MF; ++m)
#pragma unroll
        for (int n = 0; n < 4; ++n)
          acc[m][n] = __builtin_amdgcn_mfma_f32_16x16x32_bf16(af[m], bfr[n], acc[m][n], 0, 0, 0);
    }
    __builtin_amdgcn_s_setprio(0);
    __builtin_amdgcn_s_barrier();
  }
#undef STAGE

  const int cr = (lane >> 4) << 2;  // C/D: col = lane&15, row = (lane>>4)*4 + i
  const int cc = lane & 15;
#pragma unroll
  for (int m = 0; m < MF; ++m) {
#pragma unroll
    for (int n = 0; n < 4; ++n) {
      int gc = n0 + cb + n * 16 + cc;
      if (gc >= Nstore) continue;
#pragma unroll
      for (int i = 0; i < 4; ++i) {
        int gr = m0 + rb + m * 16 + cr + i;
        if (gr < M) Cb[(size_t)gr * ldC + gc] = (bf16)acc[m][n][i];
      }
    }
  }
}

// ---------------- wave-per-edge aggregation (bf16, C=512), unroll-2 ----------------
__global__ __launch_bounds__(256) void edge_agg_w(
    const bf16* __restrict__ Y, const int* __restrict__ eoff, const int* __restrict__ evtx,
    const float* __restrict__ degE, bf16* __restrict__ Xe, int nE) {
  const int wv = (blockIdx.x * 256 + threadIdx.x) >> 6;
  if (wv >= nE) return;
  const int lane = threadIdx.x & 63;
  const int beg = eoff[wv], end = eoff[wv + 1];
  const int cnt = end - beg;
  const float scale = (cnt > 0) ? degE[wv] / (float)cnt : 0.f;
  float acc[8] = {0.f, 0.f, 0.f, 0.f, 0.f, 0.f, 0.f, 0.f};
  for (int base = beg; base < end; base += 64) {
    const int nb = min(64, end - base);
    int myidx = (lane < nb) ? evtx[base + lane] : 0;
    int j = 0;
    for (; j + 1 < nb; j += 2) {
      const int i0 = __shfl(myidx, j);
      const int i1 = __shfl(myidx, j + 1);
      bf16x8 v0 = *(const bf16x8*)(Y + (size_t)i0 * 512 + lane * 8);
      bf16x8 v1 = *(const bf16x8*)(Y + (size_t)i1 * 512 + lane * 8);
#pragma unroll
      for (int q = 0; q < 8; ++q) acc[q] += (float)v0[q] + (float)v1[q];
    }
    if (j < nb) {
      const int i0 = __shfl(myidx, j);
      bf16x8 v0 = *(const bf16x8*)(Y + (size_t)i0 * 512 + lane * 8);
#pragma unroll
      for (int q = 0; q < 8; ++q) acc[q] += (float)v0[q];
    }
  }
  bf16x8 o;
#pragma unroll
  for (int q = 0; q < 8; ++q) o[q] = (bf16)(acc[q] * scale);
  *(bf16x8*)(Xe + (size_t)wv * 512 + lane * 8) = o;
}

// ---------------- wave-per-vertex aggregation (bf16, relu, C=512), unroll-2 ----------------
__global__ __launch_bounds__(256) void vtx_agg_w(
    const bf16* __restrict__ Xe, const int* __restrict__ voff, const int* __restrict__ vedg,
    const float* __restrict__ degV, bf16* __restrict__ outB, int nV) {
  const int wv = (blockIdx.x * 256 + threadIdx.x) >> 6;
  if (wv >= nV) return;
  const int lane = threadIdx.x & 63;
  const int beg = voff[wv], end = voff[wv + 1];
  const float dv = degV[wv];
  float acc[8] = {0.f, 0.f, 0.f, 0.f, 0.f, 0.f, 0.f, 0.f};
  for (int base = beg; base < end; base += 64) {
    const int nb = min(64, end - base);
    int myidx = (lane < nb) ? vedg[base + lane] : 0;
    int j = 0;
    for (; j + 1 < nb; j += 2) {
      const int i0 = __shfl(myidx, j);
      const int i1 = __shfl(myidx, j + 1);
      bf16x8 v0 = *(const bf16x8*)(Xe + (size_t)i0 * 512 + lane * 8);
      bf16x8 v1 = *(const bf16x8*)(Xe + (size_t)i1 * 512 + lane * 8);
#pragma unroll
      for (int q = 0; q < 8; ++q) acc[q] += (float)v0[q] + (float)v1[q];
    }
    if (j < nb) {
      const int i0 = __shfl(myidx, j);
      bf16x8 v0 = *(const bf16x8*)(Xe + (size_t)i0 * 512 + lane * 8);
#pragma unroll
      for (int q = 0; q < 8; ++q) acc[q] += (float)v0[q];
    }
  }
  bf16x8 o;
#pragma unroll
  for (int q = 0; q < 8; ++q) o[q] = (bf16)fmaxf(acc[q] * dv, 0.f);
  *(bf16x8*)(outB + (size_t)wv * 512 + lane * 8) = o;
}

// ---------------- wave-per-edge aggregation bf16 (layer 3, C=40) ----------------
__global__ __launch_bounds__(256) void edge_agg40_w(
    const bf16* __restrict__ Y, const int* __restrict__ eoff, const int* __restrict__ evtx,
    const float* __restrict__ degE, bf16* __restrict__ Xe, int nE) {
  const int wv = (blockIdx.x * 256 + threadIdx.x) >> 6;
  if (wv >= nE) return;
  const int lane = threadIdx.x & 63;
  const int beg = eoff[wv], end = eoff[wv + 1];
  const int cnt = end - beg;
  const float scale = (cnt > 0) ? degE[wv] / (float)cnt : 0.f;
  float a0 = 0.f;
  for (int base = beg; base < end; base += 64) {
    const int nb = min(64, end - base);
    int myidx = (lane < nb) ? evtx[base + lane] : 0;
    int j = 0;
    for (; j + 3 < nb; j += 4) {
      const int i0 = __shfl(myidx, j);
      const int i1 = __shfl(myidx, j + 1);
      const int i2 = __shfl(myidx, j + 2);
      const int i3 = __shfl(myidx, j + 3);
      if (lane < 40) {
        float x0 = (float)Y[(size_t)i0 * 40 + lane];
        float x1 = (float)Y[(size_t)i1 * 40 + lane];
        float x2 = (float)Y[(size_t)i2 * 40 + lane];
        float x3 = (float)Y[(size_t)i3 * 40 + lane];
        a0 += (x0 + x1) + (x2 + x3);
      }
    }
    for (; j < nb; ++j) {
      const int i0 = __shfl(myidx, j);
      if (lane < 40) a0 += (float)Y[(size_t)i0 * 40 + lane];
    }
  }
  if (lane < 40) Xe[(size_t)wv * 40 + lane] = (bf16)(a0 * scale);
}

// ---------------- final vertex aggregation + log_softmax (C=40) ----------------
__global__ __launch_bounds__(256) void vtx_agg_lsm(
    const bf16* __restrict__ Xe, const int* __restrict__ voff, const int* __restrict__ vedg,
    const float* __restrict__ degV, float* __restrict__ out, int nV) {
  const int wv = (blockIdx.x * 256 + threadIdx.x) >> 6;
  if (wv >= nV) return;
  const int lane = threadIdx.x & 63;
  const int beg = voff[wv], end = voff[wv + 1];
  const float dv = degV[wv];
  float a0 = 0.f;
  for (int base = beg; base < end; base += 64) {
    const int nb = min(64, end - base);
    int myidx = (lane < nb) ? vedg[base + lane] : 0;
    int j = 0;
    for (; j + 3 < nb; j += 4) {
      const int i0 = __shfl(myidx, j);
      const int i1 = __shfl(myidx, j + 1);
      const int i2 = __shfl(myidx, j + 2);
      const int i3 = __shfl(myidx, j + 3);
      if (lane < 40) {
        float x0 = (float)Xe[(size_t)i0 * 40 + lane];
        float x1 = (float)Xe[(size_t)i1 * 40 + lane];
        float x2 = (float)Xe[(size_t)i2 * 40 + lane];
        float x3 = (float)Xe[(size_t)i3 * 40 + lane];
        a0 += (x0 + x1) + (x2 + x3);
      }
    }
    for (; j < nb; ++j) {
      const int i0 = __shfl(myidx, j);
      if (lane < 40) a0 += (float)Xe[(size_t)i0 * 40 + lane];
    }
  }
  a0 *= dv;
  float val = (lane < 40) ? a0 : -3.4e38f;
  float m = val;
#pragma unroll
  for (int o = 32; o > 0; o >>= 1) m = fmaxf(m, __shfl_xor(m, o));
  float ex = (lane < 40) ? expf(val - m) : 0.f;
  float s = ex;
#pragma unroll
  for (int o = 32; o > 0; o >>= 1) s += __shfl_xor(s, o);
  float ls = logf(s);
  if (lane < 40) out[(size_t)wv * 40 + lane] = val - m - ls;
}

extern "C" void kernel_launch(void* const* d_in, const int* in_sizes, int n_in,
                              void* d_out, int out_size, void* d_ws, size_t ws_size,
                              hipStream_t stream) {
  (void)in_sizes; (void)n_in; (void)out_size; (void)ws_size;
  const float* X = (const float*)d_in[0];
  const int* vertex = (const int*)d_in[1];
  const int* edges = (const int*)d_in[2];
  const float* W1 = (const float*)d_in[3];
  const float* W2 = (const float*)d_in[4];
  const float* Wout = (const float*)d_in[5];
  const float* degE = (const float*)d_in[6];
  const float* degV = (const float*)d_in[7];
  float* out = (float*)d_out;

  char* ws = (char*)d_ws;
  size_t off = 0;
  auto alloc = [&](size_t bytes) -> void* {
    void* p = ws + off;
    off += (bytes + 255) & ~(size_t)255;
    return p;
  };
  bf16* Xb  = (bf16*)alloc((size_t)N_NODES * 512 * sizeof(bf16));
  bf16* Yb  = (bf16*)alloc((size_t)N_NODES * 512 * sizeof(bf16));
  bf16* XeB = (bf16*)alloc((size_t)N_EDGES_C * 512 * sizeof(bf16));
  bf16* Y40b  = (bf16*)alloc((size_t)N_NODES * 40 * sizeof(bf16));
  bf16* Xe40b = (bf16*)alloc((size_t)N_EDGES_C * 40 * sizeof(bf16));
  bf16* Wt1 = (bf16*)alloc((size_t)512 * 512 * sizeof(bf16));
  bf16* Wt2 = (bf16*)alloc((size_t)512 * 512 * sizeof(bf16));
  bf16* Wt3 = (bf16*)alloc((size_t)128 * 512 * sizeof(bf16));
  int* eoff = (int*)alloc((N_EDGES_C + 1) * sizeof(int));
  int* voff = (int*)alloc((N_NODES + 1) * sizeof(int));
  int* evtx = (int*)alloc((size_t)NNZ_C * sizeof(int));
  int* vedg = (int*)alloc((size_t)NNZ_C * sizeof(int));
  int* cnts = (int*)alloc((size_t)(2 * (N_EDGES_C + N_NODES)) * sizeof(int));
  int* cntE = cnts;
  int* cntV = cnts + N_EDGES_C;
  int* curE = cnts + N_EDGES_C + N_NODES;
  int* curV = cnts + 2 * N_EDGES_C + N_NODES;
  int* partE = (int*)alloc(64 * sizeof(int));
  int* partV = (int*)alloc(64 * sizeof(int));

  hipMemsetAsync(cnts, 0, (size_t)(2 * (N_EDGES_C + N_NODES)) * sizeof(int), stream);

  prep_conv<<<2304 + 12500, 256, 0, stream>>>(W1, W2, Wout, X, Wt1, Wt2, Wt3, Xb);

  hist_kernel<<<(NNZ_C + 255) / 256, 256, 0, stream>>>(vertex, edges, cntV, cntE, NNZ_C);

  const int nbE = (N_EDGES_C + SCHUNK - 1) / SCHUNK;  // 13
  const int nbV = (N_NODES + SCHUNK - 1) / SCHUNK;    // 25
  scan_part2<<<nbE + nbV, 256, 0, stream>>>(cntE, cntV, partE, partV, nbE);
  scan_mid2<<<1, 128, 0, stream>>>(partE, partV, eoff, voff, nbE, nbV);
  scan_final2<<<nbE + nbV, 256, 0, stream>>>(cntE, cntV, partE, partV, eoff, voff, nbE);

  scatter_kernel<<<(NNZ_C + 255) / 256, 256, 0, stream>>>(vertex, edges, eoff, voff,
                                                          curE, curV, evtx, vedg, NNZ_C);

  const int MB = (N_NODES + 127) / 128;          // 391
  const int G512 = ((MB * 4 + 7) / 8) * 8;       // 1568 (multiple of 8)
  const int G64  = ((MB + 7) / 8) * 8;           // 392

  // ---- layer 1 ----
  gemm_bf16_kernel<128><<<G512, 256, 0, stream>>>(Xb, Wt1, Yb, N_NODES, 512, 512, 512);
  edge_agg_w<<<(N_EDGES_C + 3) / 4, 256, 0, stream>>>(Yb, eoff, evtx, degE, XeB, N_EDGES_C);
  vtx_agg_w<<<(N_NODES + 3) / 4, 256, 0, stream>>>(XeB, voff, vedg, degV, Xb, N_NODES);

  // ---- layer 2 ----
  gemm_bf16_kernel<128><<<G512, 256, 0, stream>>>(Xb, Wt2, Yb, N_NODES, 512, 512, 512);
  edge_agg_w<<<(N_EDGES_C + 3) / 4, 256, 0, stream>>>(Yb, eoff, evtx, degE, XeB, N_EDGES_C);
  vtx_agg_w<<<(N_NODES + 3) / 4, 256, 0, stream>>>(XeB, voff, vedg, degV, Xb, N_NODES);

  // ---- layer 3 (C=40, TN=64 tile) ----
  gemm_bf16_kernel<64><<<G64, 256, 0, stream>>>(Xb, Wt3, Y40b, N_NODES, 512, 40, 40);
  edge_agg40_w<<<(N_EDGES_C + 3) / 4, 256, 0, stream>>>(Y40b, eoff, evtx, degE, Xe40b, N_EDGES_C);
  vtx_agg_lsm<<<(N_NODES + 3) / 4, 256, 0, stream>>>(Xe40b, voff, vedg, degV, out, N_NODES);
}

// Round 12
// 498.367 us; speedup vs baseline: 1.0910x; 1.0008x over previous
//
#include <hip/hip_runtime.h>

#define N_NODES 50000
#define N_EDGES_C 25000
#define NNZ_C 400000
#define SCHUNK 2048

typedef __bf16 bf16;
typedef __bf16 bf16x8 __attribute__((ext_vector_type(8)));
typedef __bf16 bf16x4 __attribute__((ext_vector_type(4)));
typedef float f32x4 __attribute__((ext_vector_type(4)));
typedef float f32x8 __attribute__((ext_vector_type(8)));

typedef __attribute__((address_space(1))) const void as1_cvoid;
typedef __attribute__((address_space(3))) void as3_void;

__device__ __forceinline__ void gload_lds16(const bf16* g, bf16* l) {
  __builtin_amdgcn_global_load_lds((as1_cvoid*)g, (as3_void*)l, 16, 0, 0);
}

// ---------------- prep: weight transposes + X f32->bf16 + incidence histogram ----------------
#define PREP_W 2304
#define PREP_X 12500
#define PREP_H ((NNZ_C + 255) / 256)
__global__ void prep_conv(const float* __restrict__ W1, const float* __restrict__ W2,
                          const float* __restrict__ Wout, const float* __restrict__ X,
                          bf16* __restrict__ Wt1, bf16* __restrict__ Wt2,
                          bf16* __restrict__ Wt3,  bf16* __restrict__ Xb,
                          const int* __restrict__ vtx, const int* __restrict__ edg,
                          int* __restrict__ cntV, int* __restrict__ cntE) {
  const int b = blockIdx.x;
  const int t = threadIdx.x;
  if (b < 1024) {                         // W1: 512x512 transpose
    int idx = b * 256 + t;
    int n = idx >> 9, k = idx & 511;
    Wt1[idx] = (bf16)W1[(size_t)k * 512 + n];
  } else if (b < 2048) {                  // W2
    int idx = (b - 1024) * 256 + t;
    int n = idx >> 9, k = idx & 511;
    Wt2[idx] = (bf16)W2[(size_t)k * 512 + n];
  } else if (b < PREP_W) {                // Wout: 128 rows x 512, cols >=40 zero
    int idx = (b - 2048) * 256 + t;
    int n = idx >> 9, k = idx & 511;
    Wt3[idx] = (n < 40) ? (bf16)Wout[(size_t)k * 40 + n] : (bf16)0.0f;
  } else if (b < PREP_W + PREP_X) {       // X convert
    size_t i = ((size_t)(b - PREP_W) * 256 + t) * 8;
    float4 v0 = *(const float4*)(X + i);
    float4 v1 = *(const float4*)(X + i + 4);
    bf16x8 o;
    o[0] = (bf16)v0.x; o[1] = (bf16)v0.y; o[2] = (bf16)v0.z; o[3] = (bf16)v0.w;
    o[4] = (bf16)v1.x; o[5] = (bf16)v1.y; o[6] = (bf16)v1.z; o[7] = (bf16)v1.w;
    *(bf16x8*)(Xb + i) = o;
  } else {                                // histogram
    int i = (b - PREP_W - PREP_X) * 256 + t;
    if (i < NNZ_C) {
      atomicAdd(&cntV[vtx[i]], 1);
      atomicAdd(&cntE[edg[i]], 1);
    }
  }
}

__global__ void scan_part2(const int* __restrict__ cntE, const int* __restrict__ cntV,
                           int* __restrict__ partE, int* __restrict__ partV,
                           int nbE) {
  __shared__ int red[256];
  const int t = threadIdx.x;
  const int isV = (blockIdx.x >= nbE);
  const int b = isV ? (blockIdx.x - nbE) : blockIdx.x;
  const int* cnt = isV ? cntV : cntE;
  const int n = isV ? N_NODES : N_EDGES_C;
  const int base = b * SCHUNK + t * 8;
  int s = 0;
#pragma unroll
  for (int q = 0; q < 8; ++q) {
    int i = base + q;
    if (i < n) s += cnt[i];
  }
  red[t] = s;
  __syncthreads();
  for (int d = 128; d > 0; d >>= 1) {
    if (t < d) red[t] += red[t + d];
    __syncthreads();
  }
  if (t == 0) (isV ? partV : partE)[b] = red[0];
}

__global__ void scan_mid2(int* __restrict__ partE, int* __restrict__ partV,
                          int* __restrict__ eoff, int* __restrict__ voff,
                          int nbE, int nbV) {
  const int wv = threadIdx.x >> 6;
  const int lane = threadIdx.x & 63;
  int* part = wv ? partV : partE;
  int* off = wv ? voff : eoff;
  const int np = wv ? nbV : nbE;
  const int n = wv ? N_NODES : N_EDGES_C;
  int orig = (lane < np) ? part[lane] : 0;
  int v = orig;
  for (int o = 1; o < 64; o <<= 1) {
    int x = __shfl_up(v, o);
    if (lane >= o) v += x;
  }
  if (lane < np) part[lane] = v - orig;
  if (lane == 63) off[n] = v;
}

__global__ void scan_final2(const int* __restrict__ cntE, const int* __restrict__ cntV,
                            const int* __restrict__ partE, const int* __restrict__ partV,
                            int* __restrict__ eoff, int* __restrict__ voff, int nbE) {
  __shared__ int tsum[256];
  const int t = threadIdx.x;
  const int isV = (blockIdx.x >= nbE);
  const int b = isV ? (blockIdx.x - nbE) : blockIdx.x;
  const int* cnt = isV ? cntV : cntE;
  const int* part = isV ? partV : partE;
  int* off = isV ? voff : eoff;
  const int n = isV ? N_NODES : N_EDGES_C;
  const int base = b * SCHUNK + t * 8;
  int loc[8];
  int s = 0;
#pragma unroll
  for (int q = 0; q < 8; ++q) {
    int i = base + q;
    loc[q] = (i < n) ? cnt[i] : 0;
    s += loc[q];
  }
  tsum[t] = s;
  __syncthreads();
  for (int d = 1; d < 256; d <<= 1) {
    int x = (t >= d) ? tsum[t - d] : 0;
    __syncthreads();
    tsum[t] += x;
    __syncthreads();
  }
  int run = part[b] + ((t > 0) ? tsum[t - 1] : 0);
#pragma unroll
  for (int q = 0; q < 8; ++q) {
    int i = base + q;
    if (i < n) off[i] = run;
    run += loc[q];
  }
}

__global__ void scatter_kernel(const int* __restrict__ vtx, const int* __restrict__ edg,
                               const int* __restrict__ eoff, const int* __restrict__ voff,
                               int* __restrict__ curE, int* __restrict__ curV,
                               int* __restrict__ evtx, int* __restrict__ vedg, int nnz) {
  int i = blockIdx.x * blockDim.x + threadIdx.x;
  if (i < nnz) {
    int e = edg[i], v = vtx[i];
    int p = atomicAdd(&curE[e], 1);
    evtx[eoff[e] + p] = v;
    int q = atomicAdd(&curV[v], 1);
    vedg[voff[v] + q] = e;
  }
}

// ---------------- GEMM: BK=64, swizzled LDS, dbuf counted-vmcnt, XCD-chunked 1-D grid ----------------
template <int TN>
__global__ __launch_bounds__(256) void gemm_bf16_kernel(
    const bf16* __restrict__ A, const bf16* __restrict__ B,
    bf16* __restrict__ Cb, int M, int K, int ldC, int Nstore) {
  __shared__ bf16 Al[2][128][64];
  __shared__ bf16 Bl[2][TN][64];
  const int bid = blockIdx.x;
  const int cpx = gridDim.x >> 3;
  const int wid = (bid & 7) * cpx + (bid >> 3);
  const int MBLK = (M + 127) >> 7;
  int mIdx, nIdx;
  if (TN == 128) { mIdx = wid >> 2; nIdx = wid & 3; }
  else           { mIdx = wid;      nIdx = 0; }
  if (mIdx >= MBLK) return;
  const int m0 = mIdx * 128;
  const int n0 = nIdx * TN;

  const int t = threadIdx.x;
  const int w = t >> 6, lane = t & 63;
  const int rb = (TN == 128) ? ((w >> 1) * 64) : (w * 32);
  const int cb = (TN == 128) ? ((w & 1) * 64) : 0;
  const int MF = (TN == 128) ? 4 : 2;
  const int lr = lane & 15;
  const int ls = lane >> 4;

  f32x4 acc[(TN == 128) ? 4 : 2][4];
#pragma unroll
  for (int m = 0; m < MF; ++m)
#pragma unroll
    for (int n = 0; n < 4; ++n) acc[m][n] = (f32x4){0.f, 0.f, 0.f, 0.f};

  const int srow8 = lane >> 3;
  const int scol = ((lane & 7) ^ srow8) << 3;

  const bf16* Abase = A + (size_t)m0 * K;
  const bf16* Bbase = B + (size_t)n0 * K;

#define STAGE(tile, bsel)                                                          \
  {                                                                                \
    const int kk_ = (tile) * 64;                                                   \
    _Pragma("unroll")                                                              \
    for (int q = 0; q < 4; ++q) {                                                  \
      const int row = w * 32 + q * 8 + srow8;                                      \
      gload_lds16(Abase + (size_t)row * K + kk_ + scol, &Al[bsel][w*32+q*8][0]);   \
    }                                                                              \
    _Pragma("unroll")                                                              \
    for (int q = 0; q < TN / 32; ++q) {                                            \
      const int row = w * (TN / 4) + q * 8 + srow8;                                \
      gload_lds16(Bbase + (size_t)row * K + kk_ + scol,                            \
                  &Bl[bsel][w * (TN / 4) + q * 8][0]);                             \
    }                                                                              \
  }

  const int NT = K >> 6;
  STAGE(0, 0);
  for (int tt = 0; tt < NT; ++tt) {
    const int cur = tt & 1;
    if (tt + 1 < NT) {
      STAGE(tt + 1, cur ^ 1);
      if (TN == 128) asm volatile("s_waitcnt vmcnt(8)" ::: "memory");
      else           asm volatile("s_waitcnt vmcnt(6)" ::: "memory");
    } else {
      asm volatile("s_waitcnt vmcnt(0)" ::: "memory");
    }
    __builtin_amdgcn_s_barrier();
    __builtin_amdgcn_s_setprio(1);
#pragma unroll
    for (int ks = 0; ks < 2; ++ks) {
      bf16x8 af[(TN == 128) ? 4 : 2], bfr[4];
#pragma unroll
      for (int m = 0; m < MF; ++m) {
        const int R = rb + m * 16 + lr;
        af[m] = *(const bf16x8*)(&Al[cur][R][((ks * 4 + ls) ^ (lr & 7)) << 3]);
      }
#pragma unroll
      for (int n = 0; n < 4; ++n) {
        const int R = cb + n * 16 + lr;
        bfr[n] = *(const bf16x8*)(&Bl[cur][R][((ks * 4 + ls) ^ (lr & 7)) << 3]);
      }
#pragma unroll
      for (int m = 0; m < MF; ++m)
#pragma unroll
        for (int n = 0; n < 4; ++n)
          acc[m][n] = __builtin_amdgcn_mfma_f32_16x16x32_bf16(af[m], bfr[n], acc[m][n], 0, 0, 0);
    }
    __builtin_amdgcn_s_setprio(0);
    __builtin_amdgcn_s_barrier();
  }
#undef STAGE

  const int cr = (lane >> 4) << 2;  // C/D: col = lane&15, row = (lane>>4)*4 + i
  const int cc = lane & 15;
#pragma unroll
  for (int m = 0; m < MF; ++m) {
#pragma unroll
    for (int n = 0; n < 4; ++n) {
      int gc = n0 + cb + n * 16 + cc;
      if (gc >= Nstore) continue;
#pragma unroll
      for (int i = 0; i < 4; ++i) {
        int gr = m0 + rb + m * 16 + cr + i;
        if (gr < M) Cb[(size_t)gr * ldC + gc] = (bf16)acc[m][n][i];
      }
    }
  }
}

// ---------------- wave-per-edge aggregation (bf16, C=512), unroll-2 ----------------
__global__ __launch_bounds__(256) void edge_agg_w(
    const bf16* __restrict__ Y, const int* __restrict__ eoff, const int* __restrict__ evtx,
    const float* __restrict__ degE, bf16* __restrict__ Xe, int nE) {
  const int wv = (blockIdx.x * 256 + threadIdx.x) >> 6;
  if (wv >= nE) return;
  const int lane = threadIdx.x & 63;
  const int beg = eoff[wv], end = eoff[wv + 1];
  const int cnt = end - beg;
  const float scale = (cnt > 0) ? degE[wv] / (float)cnt : 0.f;
  float acc[8] = {0.f, 0.f, 0.f, 0.f, 0.f, 0.f, 0.f, 0.f};
  for (int base = beg; base < end; base += 64) {
    const int nb = min(64, end - base);
    int myidx = (lane < nb) ? evtx[base + lane] : 0;
    int j = 0;
    for (; j + 1 < nb; j += 2) {
      const int i0 = __shfl(myidx, j);
      const int i1 = __shfl(myidx, j + 1);
      bf16x8 v0 = *(const bf16x8*)(Y + (size_t)i0 * 512 + lane * 8);
      bf16x8 v1 = *(const bf16x8*)(Y + (size_t)i1 * 512 + lane * 8);
#pragma unroll
      for (int q = 0; q < 8; ++q) acc[q] += (float)v0[q] + (float)v1[q];
    }
    if (j < nb) {
      const int i0 = __shfl(myidx, j);
      bf16x8 v0 = *(const bf16x8*)(Y + (size_t)i0 * 512 + lane * 8);
#pragma unroll
      for (int q = 0; q < 8; ++q) acc[q] += (float)v0[q];
    }
  }
  bf16x8 o;
#pragma unroll
  for (int q = 0; q < 8; ++q) o[q] = (bf16)(acc[q] * scale);
  *(bf16x8*)(Xe + (size_t)wv * 512 + lane * 8) = o;
}

// ---------------- wave-per-vertex aggregation (bf16, relu, C=512), unroll-2 ----------------
__global__ __launch_bounds__(256) void vtx_agg_w(
    const bf16* __restrict__ Xe, const int* __restrict__ voff, const int* __restrict__ vedg,
    const float* __restrict__ degV, bf16* __restrict__ outB, int nV) {
  const int wv = (blockIdx.x * 256 + threadIdx.x) >> 6;
  if (wv >= nV) return;
  const int lane = threadIdx.x & 63;
  const int beg = voff[wv], end = voff[wv + 1];
  const float dv = degV[wv];
  float acc[8] = {0.f, 0.f, 0.f, 0.f, 0.f, 0.f, 0.f, 0.f};
  for (int base = beg; base < end; base += 64) {
    const int nb = min(64, end - base);
    int myidx = (lane < nb) ? vedg[base + lane] : 0;
    int j = 0;
    for (; j + 1 < nb; j += 2) {
      const int i0 = __shfl(myidx, j);
      const int i1 = __shfl(myidx, j + 1);
      bf16x8 v0 = *(const bf16x8*)(Xe + (size_t)i0 * 512 + lane * 8);
      bf16x8 v1 = *(const bf16x8*)(Xe + (size_t)i1 * 512 + lane * 8);
#pragma unroll
      for (int q = 0; q < 8; ++q) acc[q] += (float)v0[q] + (float)v1[q];
    }
    if (j < nb) {
      const int i0 = __shfl(myidx, j);
      bf16x8 v0 = *(const bf16x8*)(Xe + (size_t)i0 * 512 + lane * 8);
#pragma unroll
      for (int q = 0; q < 8; ++q) acc[q] += (float)v0[q];
    }
  }
  bf16x8 o;
#pragma unroll
  for (int q = 0; q < 8; ++q) o[q] = (bf16)fmaxf(acc[q] * dv, 0.f);
  *(bf16x8*)(outB + (size_t)wv * 512 + lane * 8) = o;
}

// ---------------- layer-3 edge aggregation, octet layout (C=64 padded, 8 rows/iter) ----------------
// lane (g,c) = (l>>3, l&7): row-group g loads octet c of row; cross-group sum via shfl_xor{8,16,32}.
__global__ __launch_bounds__(256) void edge_agg40_w8(
    const bf16* __restrict__ Y, const int* __restrict__ eoff, const int* __restrict__ evtx,
    const float* __restrict__ degE, bf16* __restrict__ Xe, int nE) {
  const int wv = (blockIdx.x * 256 + threadIdx.x) >> 6;
  if (wv >= nE) return;
  const int lane = threadIdx.x & 63;
  const int g = lane >> 3, c = lane & 7;
  const int beg = eoff[wv], end = eoff[wv + 1];
  const int cnt = end - beg;
  const float scale = (cnt > 0) ? degE[wv] / (float)cnt : 0.f;
  float acc[8] = {0.f, 0.f, 0.f, 0.f, 0.f, 0.f, 0.f, 0.f};
  for (int base = beg; base < end; base += 64) {
    const int nb = min(64, end - base);
    int myidx = (lane < nb) ? evtx[base + lane] : 0;
    for (int inner = 0; inner < 8; ++inner) {
      const int r = inner * 8 + g;
      if (inner * 8 >= nb) break;
      const int ridx = __shfl(myidx, r);
      if (r < nb) {
        bf16x8 v = *(const bf16x8*)(Y + (size_t)ridx * 64 + c * 8);
#pragma unroll
        for (int q = 0; q < 8; ++q) acc[q] += (float)v[q];
      }
    }
  }
#pragma unroll
  for (int o = 8; o < 64; o <<= 1)
#pragma unroll
    for (int q = 0; q < 8; ++q) acc[q] += __shfl_xor(acc[q], o);
  if (lane < 8) {
    bf16x8 o;
#pragma unroll
    for (int q = 0; q < 8; ++q) o[q] = (bf16)(acc[q] * scale);
    *(bf16x8*)(Xe + (size_t)wv * 64 + lane * 8) = o;
  }
}

// ---------------- final vertex aggregation + log_softmax, octet layout ----------------
__global__ __launch_bounds__(256) void vtx_agg_lsm8(
    const bf16* __restrict__ Xe, const int* __restrict__ voff, const int* __restrict__ vedg,
    const float* __restrict__ degV, float* __restrict__ out, int nV) {
  const int wv = (blockIdx.x * 256 + threadIdx.x) >> 6;
  if (wv >= nV) return;
  const int lane = threadIdx.x & 63;
  const int g = lane >> 3, c = lane & 7;
  const int beg = voff[wv], end = voff[wv + 1];
  const float dv = degV[wv];
  float acc[8] = {0.f, 0.f, 0.f, 0.f, 0.f, 0.f, 0.f, 0.f};
  for (int base = beg; base < end; base += 64) {
    const int nb = min(64, end - base);
    int myidx = (lane < nb) ? vedg[base + lane] : 0;
    for (int inner = 0; inner < 8; ++inner) {
      const int r = inner * 8 + g;
      if (inner * 8 >= nb) break;
      const int ridx = __shfl(myidx, r);
      if (r < nb) {
        bf16x8 v = *(const bf16x8*)(Xe + (size_t)ridx * 64 + c * 8);
#pragma unroll
        for (int q = 0; q < 8; ++q) acc[q] += (float)v[q];
      }
    }
  }
#pragma unroll
  for (int o = 8; o < 64; o <<= 1)
#pragma unroll
    for (int q = 0; q < 8; ++q) acc[q] += __shfl_xor(acc[q], o);
  // logits (octet c valid iff c<5); softmax across octets via shfl_xor{1,2,4}
  float l[8];
#pragma unroll
  for (int q = 0; q < 8; ++q) l[q] = acc[q] * dv;
  float lm = -3.4e38f;
  if (c < 5) {
#pragma unroll
    for (int q = 0; q < 8; ++q) lm = fmaxf(lm, l[q]);
  }
#pragma unroll
  for (int o = 1; o < 8; o <<= 1) lm = fmaxf(lm, __shfl_xor(lm, o));
  float ls = 0.f;
  if (c < 5) {
#pragma unroll
    for (int q = 0; q < 8; ++q) ls += expf(l[q] - lm);
  }
#pragma unroll
  for (int o = 1; o < 8; o <<= 1) ls += __shfl_xor(ls, o);
  const float lg = logf(ls);
  if (lane < 5) {
    f32x8 w;
#pragma unroll
    for (int q = 0; q < 8; ++q) w[q] = l[q] - lm - lg;
    *(f32x8*)(out + (size_t)wv * 40 + lane * 8) = w;
  }
}

extern "C" void kernel_launch(void* const* d_in, const int* in_sizes, int n_in,
                              void* d_out, int out_size, void* d_ws, size_t ws_size,
                              hipStream_t stream) {
  (void)in_sizes; (void)n_in; (void)out_size; (void)ws_size;
  const float* X = (const float*)d_in[0];
  const int* vertex = (const int*)d_in[1];
  const int* edges = (const int*)d_in[2];
  const float* W1 = (const float*)d_in[3];
  const float* W2 = (const float*)d_in[4];
  const float* Wout = (const float*)d_in[5];
  const float* degE = (const float*)d_in[6];
  const float* degV = (const float*)d_in[7];
  float* out = (float*)d_out;

  char* ws = (char*)d_ws;
  size_t off = 0;
  auto alloc = [&](size_t bytes) -> void* {
    void* p = ws + off;
    off += (bytes + 255) & ~(size_t)255;
    return p;
  };
  bf16* Xb  = (bf16*)alloc((size_t)N_NODES * 512 * sizeof(bf16));
  bf16* Yb  = (bf16*)alloc((size_t)N_NODES * 512 * sizeof(bf16));
  bf16* XeB = (bf16*)alloc((size_t)N_EDGES_C * 512 * sizeof(bf16));
  bf16* Y40b  = (bf16*)alloc((size_t)N_NODES * 64 * sizeof(bf16));
  bf16* Xe40b = (bf16*)alloc((size_t)N_EDGES_C * 64 * sizeof(bf16));
  bf16* Wt1 = (bf16*)alloc((size_t)512 * 512 * sizeof(bf16));
  bf16* Wt2 = (bf16*)alloc((size_t)512 * 512 * sizeof(bf16));
  bf16* Wt3 = (bf16*)alloc((size_t)128 * 512 * sizeof(bf16));
  int* eoff = (int*)alloc((N_EDGES_C + 1) * sizeof(int));
  int* voff = (int*)alloc((N_NODES + 1) * sizeof(int));
  int* evtx = (int*)alloc((size_t)NNZ_C * sizeof(int));
  int* vedg = (int*)alloc((size_t)NNZ_C * sizeof(int));
  int* cnts = (int*)alloc((size_t)(2 * (N_EDGES_C + N_NODES)) * sizeof(int));
  int* cntE = cnts;
  int* cntV = cnts + N_EDGES_C;
  int* curE = cnts + N_EDGES_C + N_NODES;
  int* curV = cnts + 2 * N_EDGES_C + N_NODES;
  int* partE = (int*)alloc(64 * sizeof(int));
  int* partV = (int*)alloc(64 * sizeof(int));

  hipMemsetAsync(cnts, 0, (size_t)(2 * (N_EDGES_C + N_NODES)) * sizeof(int), stream);

  // prep: weights + X convert + incidence histogram, one launch
  prep_conv<<<PREP_W + PREP_X + PREP_H, 256, 0, stream>>>(
      W1, W2, Wout, X, Wt1, Wt2, Wt3, Xb, vertex, edges, cntV, cntE);

  const int nbE = (N_EDGES_C + SCHUNK - 1) / SCHUNK;  // 13
  const int nbV = (N_NODES + SCHUNK - 1) / SCHUNK;    // 25
  scan_part2<<<nbE + nbV, 256, 0, stream>>>(cntE, cntV, partE, partV, nbE);
  scan_mid2<<<1, 128, 0, stream>>>(partE, partV, eoff, voff, nbE, nbV);
  scan_final2<<<nbE + nbV, 256, 0, stream>>>(cntE, cntV, partE, partV, eoff, voff, nbE);

  scatter_kernel<<<(NNZ_C + 255) / 256, 256, 0, stream>>>(vertex, edges, eoff, voff,
                                                          curE, curV, evtx, vedg, NNZ_C);

  const int MB = (N_NODES + 127) / 128;          // 391
  const int G512 = ((MB * 4 + 7) / 8) * 8;       // multiple of 8
  const int G64  = ((MB + 7) / 8) * 8;

  // ---- layer 1 ----
  gemm_bf16_kernel<128><<<G512, 256, 0, stream>>>(Xb, Wt1, Yb, N_NODES, 512, 512, 512);
  edge_agg_w<<<(N_EDGES_C + 3) / 4, 256, 0, stream>>>(Yb, eoff, evtx, degE, XeB, N_EDGES_C);
  vtx_agg_w<<<(N_NODES + 3) / 4, 256, 0, stream>>>(XeB, voff, vedg, degV, Xb, N_NODES);

  // ---- layer 2 ----
  gemm_bf16_kernel<128><<<G512, 256, 0, stream>>>(Xb, Wt2, Yb, N_NODES, 512, 512, 512);
  edge_agg_w<<<(N_EDGES_C + 3) / 4, 256, 0, stream>>>(Yb, eoff, evtx, degE, XeB, N_EDGES_C);
  vtx_agg_w<<<(N_NODES + 3) / 4, 256, 0, stream>>>(XeB, voff, vedg, degV, Xb, N_NODES);

  // ---- layer 3 (padded to 64 channels; cols 40..63 are zero) ----
  gemm_bf16_kernel<64><<<G64, 256, 0, stream>>>(Xb, Wt3, Y40b, N_NODES, 512, 64, 64);
  edge_agg40_w8<<<(N_EDGES_C + 3) / 4, 256, 0, stream>>>(Y40b, eoff, evtx, degE, Xe40b, N_EDGES_C);
  vtx_agg_lsm8<<<(N_NODES + 3) / 4, 256, 0, stream>>>(Xe40b, voff, vedg, degV, out, N_NODES);
}

// Round 14
// 495.145 us; speedup vs baseline: 1.0981x; 1.0065x over previous
//
#include <hip/hip_runtime.h>

#define N_NODES 50000
#define N_EDGES_C 25000
#define NNZ_C 400000
#define SCHUNK 2048

typedef __bf16 bf16;
typedef __bf16 bf16x8 __attribute__((ext_vector_type(8)));
typedef __bf16 bf16x4 __attribute__((ext_vector_type(4)));
typedef float f32x4 __attribute__((ext_vector_type(4)));
typedef float f32x8 __attribute__((ext_vector_type(8)));

typedef __attribute__((address_space(1))) const void as1_cvoid;
typedef __attribute__((address_space(3))) void as3_void;

__device__ __forceinline__ void gload_lds16(const bf16* g, bf16* l) {
  __builtin_amdgcn_global_load_lds((as1_cvoid*)g, (as3_void*)l, 16, 0, 0);
}

// ---------------- prep: histogram (first, overlaps) + tiled W transposes + X convert ----------------
// block ranges: [0,PREP_H) hist | [PREP_T1,PREP_T2) W1 tiles | [PREP_T2,PREP_WO) W2 tiles |
//               [PREP_WO,PREP_X) Wout elementwise | [PREP_X,PREP_TOTAL) X convert
#define PREP_H ((NNZ_C + 255) / 256)           // 1563 histogram blocks
#define PREP_T1 (PREP_H)                       // W1: 64 tile blocks start
#define PREP_T2 (PREP_T1 + 64)                 // W2: 64 tile blocks start
#define PREP_WO (PREP_T2 + 64)                 // Wout: 128 blocks start
#define PREP_X  (PREP_WO + 128)                // X convert start
#define PREP_TOTAL (PREP_X + 12500)
__global__ void prep_conv(const float* __restrict__ W1, const float* __restrict__ W2,
                          const float* __restrict__ Wout, const float* __restrict__ X,
                          bf16* __restrict__ Wt1, bf16* __restrict__ Wt2,
                          bf16* __restrict__ Wt3,  bf16* __restrict__ Xb,
                          const int* __restrict__ vtx, const int* __restrict__ edg,
                          int* __restrict__ cntV, int* __restrict__ cntE) {
  const int b = blockIdx.x;
  const int t = threadIdx.x;
  if (b < PREP_H) {                       // histogram (first -> overlaps streaming blocks)
    int i = b * 256 + t;
    if (i < NNZ_C) {
      atomicAdd(&cntV[vtx[i]], 1);
      atomicAdd(&cntE[edg[i]], 1);
    }
  } else if (b < PREP_WO) {               // W1/W2: 64x64 LDS-tiled transpose (64+64 blocks)
    const int isW1 = (b < PREP_T2);
    const float* W = isW1 ? W1 : W2;
    bf16* Wt = isW1 ? Wt1 : Wt2;
    const int tb = isW1 ? (b - PREP_T1) : (b - PREP_T2);
    const int k0 = (tb & 7) * 64, n0 = (tb >> 3) * 64;
    __shared__ float tile[64][65];
#pragma unroll
    for (int i = 0; i < 16; ++i) {
      int li = i * 256 + t;
      int kr = li >> 6, nc = li & 63;
      tile[kr][nc] = W[(size_t)(k0 + kr) * 512 + n0 + nc];   // coalesced read
    }
    __syncthreads();
#pragma unroll
    for (int i = 0; i < 16; ++i) {
      int lo = i * 256 + t;
      int nr = lo >> 6, kc = lo & 63;
      Wt[(size_t)(n0 + nr) * 512 + k0 + kc] = (bf16)tile[kc][nr];  // coalesced write
    }
  } else if (b < PREP_X) {                // Wout: 64 rows x 512, cols >=40 zero
    int idx = (b - PREP_WO) * 256 + t;
    int n = idx >> 9, k = idx & 511;
    Wt3[idx] = (n < 40) ? (bf16)Wout[(size_t)k * 40 + n] : (bf16)0.0f;
  } else {                                // X convert f32 -> bf16
    size_t i = ((size_t)(b - PREP_X) * 256 + t) * 8;
    float4 v0 = *(const float4*)(X + i);
    float4 v1 = *(const float4*)(X + i + 4);
    bf16x8 o;
    o[0] = (bf16)v0.x; o[1] = (bf16)v0.y; o[2] = (bf16)v0.z; o[3] = (bf16)v0.w;
    o[4] = (bf16)v1.x; o[5] = (bf16)v1.y; o[6] = (bf16)v1.z; o[7] = (bf16)v1.w;
    *(bf16x8*)(Xb + i) = o;
  }
}

__global__ void scan_part2(const int* __restrict__ cntE, const int* __restrict__ cntV,
                           int* __restrict__ partE, int* __restrict__ partV,
                           int nbE) {
  __shared__ int red[256];
  const int t = threadIdx.x;
  const int isV = (blockIdx.x >= nbE);
  const int b = isV ? (blockIdx.x - nbE) : blockIdx.x;
  const int* cnt = isV ? cntV : cntE;
  const int n = isV ? N_NODES : N_EDGES_C;
  const int base = b * SCHUNK + t * 8;
  int s = 0;
#pragma unroll
  for (int q = 0; q < 8; ++q) {
    int i = base + q;
    if (i < n) s += cnt[i];
  }
  red[t] = s;
  __syncthreads();
  for (int d = 128; d > 0; d >>= 1) {
    if (t < d) red[t] += red[t + d];
    __syncthreads();
  }
  if (t == 0) (isV ? partV : partE)[b] = red[0];
}

__global__ void scan_mid2(int* __restrict__ partE, int* __restrict__ partV,
                          int* __restrict__ eoff, int* __restrict__ voff,
                          int nbE, int nbV) {
  const int wv = threadIdx.x >> 6;
  const int lane = threadIdx.x & 63;
  int* part = wv ? partV : partE;
  int* off = wv ? voff : eoff;
  const int np = wv ? nbV : nbE;
  const int n = wv ? N_NODES : N_EDGES_C;
  int orig = (lane < np) ? part[lane] : 0;
  int v = orig;
  for (int o = 1; o < 64; o <<= 1) {
    int x = __shfl_up(v, o);
    if (lane >= o) v += x;
  }
  if (lane < np) part[lane] = v - orig;
  if (lane == 63) off[n] = v;
}

__global__ void scan_final2(const int* __restrict__ cntE, const int* __restrict__ cntV,
                            const int* __restrict__ partE, const int* __restrict__ partV,
                            int* __restrict__ eoff, int* __restrict__ voff, int nbE) {
  __shared__ int tsum[256];
  const int t = threadIdx.x;
  const int isV = (blockIdx.x >= nbE);
  const int b = isV ? (blockIdx.x - nbE) : blockIdx.x;
  const int* cnt = isV ? cntV : cntE;
  const int* part = isV ? partV : partE;
  int* off = isV ? voff : eoff;
  const int n = isV ? N_NODES : N_EDGES_C;
  const int base = b * SCHUNK + t * 8;
  int loc[8];
  int s = 0;
#pragma unroll
  for (int q = 0; q < 8; ++q) {
    int i = base + q;
    loc[q] = (i < n) ? cnt[i] : 0;
    s += loc[q];
  }
  tsum[t] = s;
  __syncthreads();
  for (int d = 1; d < 256; d <<= 1) {
    int x = (t >= d) ? tsum[t - d] : 0;
    __syncthreads();
    tsum[t] += x;
    __syncthreads();
  }
  int run = part[b] + ((t > 0) ? tsum[t - 1] : 0);
#pragma unroll
  for (int q = 0; q < 8; ++q) {
    int i = base + q;
    if (i < n) off[i] = run;
    run += loc[q];
  }
}

__global__ void scatter_kernel(const int* __restrict__ vtx, const int* __restrict__ edg,
                               const int* __restrict__ eoff, const int* __restrict__ voff,
                               int* __restrict__ curE, int* __restrict__ curV,
                               int* __restrict__ evtx, int* __restrict__ vedg, int nnz) {
  int i = blockIdx.x * blockDim.x + threadIdx.x;
  if (i < nnz) {
    int e = edg[i], v = vtx[i];
    int p = atomicAdd(&curE[e], 1);
    evtx[eoff[e] + p] = v;
    int q = atomicAdd(&curV[v], 1);
    vedg[voff[v] + q] = e;
  }
}

// ---------------- GEMM: BK=64, swizzled LDS, dbuf counted-vmcnt, XCD-chunked 1-D grid ----------------
template <int TN>
__global__ __launch_bounds__(256) void gemm_bf16_kernel(
    const bf16* __restrict__ A, const bf16* __restrict__ B,
    bf16* __restrict__ Cb, int M, int K, int ldC, int Nstore) {
  __shared__ bf16 Al[2][128][64];
  __shared__ bf16 Bl[2][TN][64];
  const int bid = blockIdx.x;
  const int cpx = gridDim.x >> 3;
  const int wid = (bid & 7) * cpx + (bid >> 3);
  const int MBLK = (M + 127) >> 7;
  int mIdx, nIdx;
  if (TN == 128) { mIdx = wid >> 2; nIdx = wid & 3; }
  else           { mIdx = wid;      nIdx = 0; }
  if (mIdx >= MBLK) return;
  const int m0 = mIdx * 128;
  const int n0 = nIdx * TN;

  const int t = threadIdx.x;
  const int w = t >> 6, lane = t & 63;
  const int rb = (TN == 128) ? ((w >> 1) * 64) : (w * 32);
  const int cb = (TN == 128) ? ((w & 1) * 64) : 0;
  const int MF = (TN == 128) ? 4 : 2;
  const int lr = lane & 15;
  const int ls = lane >> 4;

  f32x4 acc[(TN == 128) ? 4 : 2][4];
#pragma unroll
  for (int m = 0; m < MF; ++m)
#pragma unroll
    for (int n = 0; n < 4; ++n) acc[m][n] = (f32x4){0.f, 0.f, 0.f, 0.f};

  const int srow8 = lane >> 3;
  const int scol = ((lane & 7) ^ srow8) << 3;

  const bf16* Abase = A + (size_t)m0 * K;
  const bf16* Bbase = B + (size_t)n0 * K;

#define STAGE(tile, bsel)                                                          \
  {                                                                                \
    const int kk_ = (tile) * 64;                                                   \
    _Pragma("unroll")                                                              \
    for (int q = 0; q < 4; ++q) {                                                  \
      const int row = w * 32 + q * 8 + srow8;                                      \
      gload_lds16(Abase + (size_t)row * K + kk_ + scol, &Al[bsel][w*32+q*8][0]);   \
    }                                                                              \
    _Pragma("unroll")                                                              \
    for (int q = 0; q < TN / 32; ++q) {                                            \
      const int row = w * (TN / 4) + q * 8 + srow8;                                \
      gload_lds16(Bbase + (size_t)row * K + kk_ + scol,                            \
                  &Bl[bsel][w * (TN / 4) + q * 8][0]);                             \
    }                                                                              \
  }

  const int NT = K >> 6;
  STAGE(0, 0);
  for (int tt = 0; tt < NT; ++tt) {
    const int cur = tt & 1;
    if (tt + 1 < NT) {
      STAGE(tt + 1, cur ^ 1);
      if (TN == 128) asm volatile("s_waitcnt vmcnt(8)" ::: "memory");
      else           asm volatile("s_waitcnt vmcnt(6)" ::: "memory");
    } else {
      asm volatile("s_waitcnt vmcnt(0)" ::: "memory");
    }
    __builtin_amdgcn_s_barrier();
    __builtin_amdgcn_s_setprio(1);
#pragma unroll
    for (int ks = 0; ks < 2; ++ks) {
      bf16x8 af[(TN == 128) ? 4 : 2], bfr[4];
#pragma unroll
      for (int m = 0; m < MF; ++m) {
        const int R = rb + m * 16 + lr;
        af[m] = *(const bf16x8*)(&Al[cur][R][((ks * 4 + ls) ^ (lr & 7)) << 3]);
      }
#pragma unroll
      for (int n = 0; n < 4; ++n) {
        const int R = cb + n * 16 + lr;
        bfr[n] = *(const bf16x8*)(&Bl[cur][R][((ks * 4 + ls) ^ (lr & 7)) << 3]);
      }
#pragma unroll
      for (int m = 0; m < MF; ++m)
#pragma unroll
        for (int n = 0; n < 4; ++n)
          acc[m][n] = __builtin_amdgcn_mfma_f32_16x16x32_bf16(af[m], bfr[n], acc[m][n], 0, 0, 0);
    }
    __builtin_amdgcn_s_setprio(0);
    __builtin_amdgcn_s_barrier();
  }
#undef STAGE

  const int cr = (lane >> 4) << 2;  // C/D: col = lane&15, row = (lane>>4)*4 + i
  const int cc = lane & 15;
#pragma unroll
  for (int m = 0; m < MF; ++m) {
#pragma unroll
    for (int n = 0; n < 4; ++n) {
      int gc = n0 + cb + n * 16 + cc;
      if (gc >= Nstore) continue;
#pragma unroll
      for (int i = 0; i < 4; ++i) {
        int gr = m0 + rb + m * 16 + cr + i;
        if (gr < M) Cb[(size_t)gr * ldC + gc] = (bf16)acc[m][n][i];
      }
    }
  }
}

// ---------------- wave-per-edge aggregation (bf16, C=512), unroll-2 ----------------
__global__ __launch_bounds__(256) void edge_agg_w(
    const bf16* __restrict__ Y, const int* __restrict__ eoff, const int* __restrict__ evtx,
    const float* __restrict__ degE, bf16* __restrict__ Xe, int nE) {
  const int wv = (blockIdx.x * 256 + threadIdx.x) >> 6;
  if (wv >= nE) return;
  const int lane = threadIdx.x & 63;
  const int beg = eoff[wv], end = eoff[wv + 1];
  const int cnt = end - beg;
  const float scale = (cnt > 0) ? degE[wv] / (float)cnt : 0.f;
  float acc[8] = {0.f, 0.f, 0.f, 0.f, 0.f, 0.f, 0.f, 0.f};
  for (int base = beg; base < end; base += 64) {
    const int nb = min(64, end - base);
    int myidx = (lane < nb) ? evtx[base + lane] : 0;
    int j = 0;
    for (; j + 1 < nb; j += 2) {
      const int i0 = __shfl(myidx, j);
      const int i1 = __shfl(myidx, j + 1);
      bf16x8 v0 = *(const bf16x8*)(Y + (size_t)i0 * 512 + lane * 8);
      bf16x8 v1 = *(const bf16x8*)(Y + (size_t)i1 * 512 + lane * 8);
#pragma unroll
      for (int q = 0; q < 8; ++q) acc[q] += (float)v0[q] + (float)v1[q];
    }
    if (j < nb) {
      const int i0 = __shfl(myidx, j);
      bf16x8 v0 = *(const bf16x8*)(Y + (size_t)i0 * 512 + lane * 8);
#pragma unroll
      for (int q = 0; q < 8; ++q) acc[q] += (float)v0[q];
    }
  }
  bf16x8 o;
#pragma unroll
  for (int q = 0; q < 8; ++q) o[q] = (bf16)(acc[q] * scale);
  *(bf16x8*)(Xe + (size_t)wv * 512 + lane * 8) = o;
}

// ---------------- wave-per-vertex aggregation (bf16, relu, C=512), unroll-2 ----------------
__global__ __launch_bounds__(256) void vtx_agg_w(
    const bf16* __restrict__ Xe, const int* __restrict__ voff, const int* __restrict__ vedg,
    const float* __restrict__ degV, bf16* __restrict__ outB, int nV) {
  const int wv = (blockIdx.x * 256 + threadIdx.x) >> 6;
  if (wv >= nV) return;
  const int lane = threadIdx.x & 63;
  const int beg = voff[wv], end = voff[wv + 1];
  const float dv = degV[wv];
  float acc[8] = {0.f, 0.f, 0.f, 0.f, 0.f, 0.f, 0.f, 0.f};
  for (int base = beg; base < end; base += 64) {
    const int nb = min(64, end - base);
    int myidx = (lane < nb) ? vedg[base + lane] : 0;
    int j = 0;
    for (; j + 1 < nb; j += 2) {
      const int i0 = __shfl(myidx, j);
      const int i1 = __shfl(myidx, j + 1);
      bf16x8 v0 = *(const bf16x8*)(Xe + (size_t)i0 * 512 + lane * 8);
      bf16x8 v1 = *(const bf16x8*)(Xe + (size_t)i1 * 512 + lane * 8);
#pragma unroll
      for (int q = 0; q < 8; ++q) acc[q] += (float)v0[q] + (float)v1[q];
    }
    if (j < nb) {
      const int i0 = __shfl(myidx, j);
      bf16x8 v0 = *(const bf16x8*)(Xe + (size_t)i0 * 512 + lane * 8);
#pragma unroll
      for (int q = 0; q < 8; ++q) acc[q] += (float)v0[q];
    }
  }
  bf16x8 o;
#pragma unroll
  for (int q = 0; q < 8; ++q) o[q] = (bf16)fmaxf(acc[q] * dv, 0.f);
  *(bf16x8*)(outB + (size_t)wv * 512 + lane * 8) = o;
}

// ---------------- layer-3 edge aggregation, octet layout (C=64 padded) ----------------
__global__ __launch_bounds__(256) void edge_agg40_w8(
    const bf16* __restrict__ Y, const int* __restrict__ eoff, const int* __restrict__ evtx,
    const float* __restrict__ degE, bf16* __restrict__ Xe, int nE) {
  const int wv = (blockIdx.x * 256 + threadIdx.x) >> 6;
  if (wv >= nE) return;
  const int lane = threadIdx.x & 63;
  const int g = lane >> 3, c = lane & 7;
  const int beg = eoff[wv], end = eoff[wv + 1];
  const int cnt = end - beg;
  const float scale = (cnt > 0) ? degE[wv] / (float)cnt : 0.f;
  float acc[8] = {0.f, 0.f, 0.f, 0.f, 0.f, 0.f, 0.f, 0.f};
  for (int base = beg; base < end; base += 64) {
    const int nb = min(64, end - base);
    int myidx = (lane < nb) ? evtx[base + lane] : 0;
    for (int inner = 0; inner < 8; ++inner) {
      const int r = inner * 8 + g;
      if (inner * 8 >= nb) break;
      const int ridx = __shfl(myidx, r);
      if (r < nb) {
        bf16x8 v = *(const bf16x8*)(Y + (size_t)ridx * 64 + c * 8);
#pragma unroll
        for (int q = 0; q < 8; ++q) acc[q] += (float)v[q];
      }
    }
  }
#pragma unroll
  for (int o = 8; o < 64; o <<= 1)
#pragma unroll
    for (int q = 0; q < 8; ++q) acc[q] += __shfl_xor(acc[q], o);
  if (lane < 8) {
    bf16x8 o;
#pragma unroll
    for (int q = 0; q < 8; ++q) o[q] = (bf16)(acc[q] * scale);
    *(bf16x8*)(Xe + (size_t)wv * 64 + lane * 8) = o;
  }
}

// ---------------- final vertex aggregation + log_softmax, octet layout ----------------
__global__ __launch_bounds__(256) void vtx_agg_lsm8(
    const bf16* __restrict__ Xe, const int* __restrict__ voff, const int* __restrict__ vedg,
    const float* __restrict__ degV, float* __restrict__ out, int nV) {
  const int wv = (blockIdx.x * 256 + threadIdx.x) >> 6;
  if (wv >= nV) return;
  const int lane = threadIdx.x & 63;
  const int g = lane >> 3, c = lane & 7;
  const int beg = voff[wv], end = voff[wv + 1];
  const float dv = degV[wv];
  float acc[8] = {0.f, 0.f, 0.f, 0.f, 0.f, 0.f, 0.f, 0.f};
  for (int base = beg; base < end; base += 64) {
    const int nb = min(64, end - base);
    int myidx = (lane < nb) ? vedg[base + lane] : 0;
    for (int inner = 0; inner < 8; ++inner) {
      const int r = inner * 8 + g;
      if (inner * 8 >= nb) break;
      const int ridx = __shfl(myidx, r);
      if (r < nb) {
        bf16x8 v = *(const bf16x8*)(Xe + (size_t)ridx * 64 + c * 8);
#pragma unroll
        for (int q = 0; q < 8; ++q) acc[q] += (float)v[q];
      }
    }
  }
#pragma unroll
  for (int o = 8; o < 64; o <<= 1)
#pragma unroll
    for (int q = 0; q < 8; ++q) acc[q] += __shfl_xor(acc[q], o);
  float l[8];
#pragma unroll
  for (int q = 0; q < 8; ++q) l[q] = acc[q] * dv;
  float lm = -3.4e38f;
  if (c < 5) {
#pragma unroll
    for (int q = 0; q < 8; ++q) lm = fmaxf(lm, l[q]);
  }
#pragma unroll
  for (int o = 1; o < 8; o <<= 1) lm = fmaxf(lm, __shfl_xor(lm, o));
  float ls = 0.f;
  if (c < 5) {
#pragma unroll
    for (int q = 0; q < 8; ++q) ls += expf(l[q] - lm);
  }
#pragma unroll
  for (int o = 1; o < 8; o <<= 1) ls += __shfl_xor(ls, o);
  const float lg = logf(ls);
  if (lane < 5) {
    f32x8 w;
#pragma unroll
    for (int q = 0; q < 8; ++q) w[q] = l[q] - lm - lg;
    *(f32x8*)(out + (size_t)wv * 40 + lane * 8) = w;
  }
}

extern "C" void kernel_launch(void* const* d_in, const int* in_sizes, int n_in,
                              void* d_out, int out_size, void* d_ws, size_t ws_size,
                              hipStream_t stream) {
  (void)in_sizes; (void)n_in; (void)out_size; (void)ws_size;
  const float* X = (const float*)d_in[0];
  const int* vertex = (const int*)d_in[1];
  const int* edges = (const int*)d_in[2];
  const float* W1 = (const float*)d_in[3];
  const float* W2 = (const float*)d_in[4];
  const float* Wout = (const float*)d_in[5];
  const float* degE = (const float*)d_in[6];
  const float* degV = (const float*)d_in[7];
  float* out = (float*)d_out;

  char* ws = (char*)d_ws;
  size_t off = 0;
  auto alloc = [&](size_t bytes) -> void* {
    void* p = ws + off;
    off += (bytes + 255) & ~(size_t)255;
    return p;
  };
  bf16* Xb  = (bf16*)alloc((size_t)N_NODES * 512 * sizeof(bf16));
  bf16* Yb  = (bf16*)alloc((size_t)N_NODES * 512 * sizeof(bf16));
  bf16* XeB = (bf16*)alloc((size_t)N_EDGES_C * 512 * sizeof(bf16));
  bf16* Y40b  = (bf16*)alloc((size_t)N_NODES * 64 * sizeof(bf16));
  bf16* Xe40b = (bf16*)alloc((size_t)N_EDGES_C * 64 * sizeof(bf16));
  bf16* Wt1 = (bf16*)alloc((size_t)512 * 512 * sizeof(bf16));
  bf16* Wt2 = (bf16*)alloc((size_t)512 * 512 * sizeof(bf16));
  bf16* Wt3 = (bf16*)alloc((size_t)64 * 512 * sizeof(bf16));
  int* eoff = (int*)alloc((N_EDGES_C + 1) * sizeof(int));
  int* voff = (int*)alloc((N_NODES + 1) * sizeof(int));
  int* evtx = (int*)alloc((size_t)NNZ_C * sizeof(int));
  int* vedg = (int*)alloc((size_t)NNZ_C * sizeof(int));
  int* cnts = (int*)alloc((size_t)(2 * (N_EDGES_C + N_NODES)) * sizeof(int));
  int* cntE = cnts;
  int* cntV = cnts + N_EDGES_C;
  int* curE = cnts + N_EDGES_C + N_NODES;
  int* curV = cnts + 2 * N_EDGES_C + N_NODES;
  int* partE = (int*)alloc(64 * sizeof(int));
  int* partV = (int*)alloc(64 * sizeof(int));

  hipMemsetAsync(cnts, 0, (size_t)(2 * (N_EDGES_C + N_NODES)) * sizeof(int), stream);

  prep_conv<<<PREP_TOTAL, 256, 0, stream>>>(
      W1, W2, Wout, X, Wt1, Wt2, Wt3, Xb, vertex, edges, cntV, cntE);

  const int nbE = (N_EDGES_C + SCHUNK - 1) / SCHUNK;  // 13
  const int nbV = (N_NODES + SCHUNK - 1) / SCHUNK;    // 25
  scan_part2<<<nbE + nbV, 256, 0, stream>>>(cntE, cntV, partE, partV, nbE);
  scan_mid2<<<1, 128, 0, stream>>>(partE, partV, eoff, voff, nbE, nbV);
  scan_final2<<<nbE + nbV, 256, 0, stream>>>(cntE, cntV, partE, partV, eoff, voff, nbE);

  scatter_kernel<<<(NNZ_C + 255) / 256, 256, 0, stream>>>(vertex, edges, eoff, voff,
                                                          curE, curV, evtx, vedg, NNZ_C);

  const int MB = (N_NODES + 127) / 128;          // 391
  const int G512 = ((MB * 4 + 7) / 8) * 8;
  const int G64  = ((MB + 7) / 8) * 8;

  // ---- layer 1 ----
  gemm_bf16_kernel<128><<<G512, 256, 0, stream>>>(Xb, Wt1, Yb, N_NODES, 512, 512, 512);
  edge_agg_w<<<(N_EDGES_C + 3) / 4, 256, 0, stream>>>(Yb, eoff, evtx, degE, XeB, N_EDGES_C);
  vtx_agg_w<<<(N_NODES + 3) / 4, 256, 0, stream>>>(XeB, voff, vedg, degV, Xb, N_NODES);

  // ---- layer 2 ----
  gemm_bf16_kernel<128><<<G512, 256, 0, stream>>>(Xb, Wt2, Yb, N_NODES, 512, 512, 512);
  edge_agg_w<<<(N_EDGES_C + 3) / 4, 256, 0, stream>>>(Yb, eoff, evtx, degE, XeB, N_EDGES_C);
  vtx_agg_w<<<(N_NODES + 3) / 4, 256, 0, stream>>>(XeB, voff, vedg, degV, Xb, N_NODES);

  // ---- layer 3 (padded to 64 channels; cols 40..63 zero) ----
  gemm_bf16_kernel<64><<<G64, 256, 0, stream>>>(Xb, Wt3, Y40b, N_NODES, 512, 64, 64);
  edge_agg40_w8<<<(N_EDGES_C + 3) / 4, 256, 0, stream>>>(Y40b, eoff, evtx, degE, Xe40b, N_EDGES_C);
  vtx_agg_lsm8<<<(N_NODES + 3) / 4, 256, 0, stream>>>(Xe40b, voff, vedg, degV, out, N_NODES);
}

// Round 15
// 454.201 us; speedup vs baseline: 1.1971x; 1.0901x over previous
//
#include <hip/hip_runtime.h>

#define N_NODES 50000
#define N_EDGES_C 25000
#define NNZ_C 400000
#define SCHUNK 2048

typedef __bf16 bf16;
typedef __bf16 bf16x8 __attribute__((ext_vector_type(8)));
typedef __bf16 bf16x4 __attribute__((ext_vector_type(4)));
typedef float f32x4 __attribute__((ext_vector_type(4)));
typedef float f32x8 __attribute__((ext_vector_type(8)));

typedef __attribute__((address_space(1))) const void as1_cvoid;
typedef __attribute__((address_space(3))) void as3_void;

__device__ __forceinline__ void gload_lds16(const bf16* g, bf16* l) {
  __builtin_amdgcn_global_load_lds((as1_cvoid*)g, (as3_void*)l, 16, 0, 0);
}

// ---------------- prep: histogram + tiled W transposes + X convert ----------------
#define PREP_H ((NNZ_C + 255) / 256)           // 1563 histogram blocks
#define PREP_T1 (PREP_H)
#define PREP_T2 (PREP_T1 + 64)
#define PREP_WO (PREP_T2 + 64)
#define PREP_X  (PREP_WO + 128)
#define PREP_TOTAL (PREP_X + 12500)
__global__ void prep_conv(const float* __restrict__ W1, const float* __restrict__ W2,
                          const float* __restrict__ Wout, const float* __restrict__ X,
                          bf16* __restrict__ Wt1, bf16* __restrict__ Wt2,
                          bf16* __restrict__ Wt3,  bf16* __restrict__ Xb,
                          const int* __restrict__ vtx, const int* __restrict__ edg,
                          int* __restrict__ cntV, int* __restrict__ cntE) {
  const int b = blockIdx.x;
  const int t = threadIdx.x;
  if (b < PREP_H) {                       // histogram
    int i = b * 256 + t;
    if (i < NNZ_C) {
      atomicAdd(&cntV[vtx[i]], 1);
      atomicAdd(&cntE[edg[i]], 1);
    }
  } else if (b < PREP_WO) {               // W1/W2: 64x64 LDS-tiled transpose
    const int isW1 = (b < PREP_T2);
    const float* W = isW1 ? W1 : W2;
    bf16* Wt = isW1 ? Wt1 : Wt2;
    const int tb = isW1 ? (b - PREP_T1) : (b - PREP_T2);
    const int k0 = (tb & 7) * 64, n0 = (tb >> 3) * 64;
    __shared__ float tile[64][65];
#pragma unroll
    for (int i = 0; i < 16; ++i) {
      int li = i * 256 + t;
      int kr = li >> 6, nc = li & 63;
      tile[kr][nc] = W[(size_t)(k0 + kr) * 512 + n0 + nc];
    }
    __syncthreads();
#pragma unroll
    for (int i = 0; i < 16; ++i) {
      int lo = i * 256 + t;
      int nr = lo >> 6, kc = lo & 63;
      Wt[(size_t)(n0 + nr) * 512 + k0 + kc] = (bf16)tile[kc][nr];
    }
  } else if (b < PREP_X) {                // Wout: 64 rows x 512, cols >=40 zero
    int idx = (b - PREP_WO) * 256 + t;
    int n = idx >> 9, k = idx & 511;
    Wt3[idx] = (n < 40) ? (bf16)Wout[(size_t)k * 40 + n] : (bf16)0.0f;
  } else {                                // X convert f32 -> bf16
    size_t i = ((size_t)(b - PREP_X) * 256 + t) * 8;
    float4 v0 = *(const float4*)(X + i);
    float4 v1 = *(const float4*)(X + i + 4);
    bf16x8 o;
    o[0] = (bf16)v0.x; o[1] = (bf16)v0.y; o[2] = (bf16)v0.z; o[3] = (bf16)v0.w;
    o[4] = (bf16)v1.x; o[5] = (bf16)v1.y; o[6] = (bf16)v1.z; o[7] = (bf16)v1.w;
    *(bf16x8*)(Xb + i) = o;
  }
}

__global__ void scan_part2(const int* __restrict__ cntE, const int* __restrict__ cntV,
                           int* __restrict__ partE, int* __restrict__ partV,
                           int nbE) {
  __shared__ int red[256];
  const int t = threadIdx.x;
  const int isV = (blockIdx.x >= nbE);
  const int b = isV ? (blockIdx.x - nbE) : blockIdx.x;
  const int* cnt = isV ? cntV : cntE;
  const int n = isV ? N_NODES : N_EDGES_C;
  const int base = b * SCHUNK + t * 8;
  int s = 0;
#pragma unroll
  for (int q = 0; q < 8; ++q) {
    int i = base + q;
    if (i < n) s += cnt[i];
  }
  red[t] = s;
  __syncthreads();
  for (int d = 128; d > 0; d >>= 1) {
    if (t < d) red[t] += red[t + d];
    __syncthreads();
  }
  if (t == 0) (isV ? partV : partE)[b] = red[0];
}

__global__ void scan_mid2(int* __restrict__ partE, int* __restrict__ partV,
                          int* __restrict__ eoff, int* __restrict__ voff,
                          int nbE, int nbV) {
  const int wv = threadIdx.x >> 6;
  const int lane = threadIdx.x & 63;
  int* part = wv ? partV : partE;
  int* off = wv ? voff : eoff;
  const int np = wv ? nbV : nbE;
  const int n = wv ? N_NODES : N_EDGES_C;
  int orig = (lane < np) ? part[lane] : 0;
  int v = orig;
  for (int o = 1; o < 64; o <<= 1) {
    int x = __shfl_up(v, o);
    if (lane >= o) v += x;
  }
  if (lane < np) part[lane] = v - orig;
  if (lane == 63) off[n] = v;
}

__global__ void scan_final2(const int* __restrict__ cntE, const int* __restrict__ cntV,
                            const int* __restrict__ partE, const int* __restrict__ partV,
                            int* __restrict__ eoff, int* __restrict__ voff, int nbE) {
  __shared__ int tsum[256];
  const int t = threadIdx.x;
  const int isV = (blockIdx.x >= nbE);
  const int b = isV ? (blockIdx.x - nbE) : blockIdx.x;
  const int* cnt = isV ? cntV : cntE;
  const int* part = isV ? partV : partE;
  int* off = isV ? voff : eoff;
  const int n = isV ? N_NODES : N_EDGES_C;
  const int base = b * SCHUNK + t * 8;
  int loc[8];
  int s = 0;
#pragma unroll
  for (int q = 0; q < 8; ++q) {
    int i = base + q;
    loc[q] = (i < n) ? cnt[i] : 0;
    s += loc[q];
  }
  tsum[t] = s;
  __syncthreads();
  for (int d = 1; d < 256; d <<= 1) {
    int x = (t >= d) ? tsum[t - d] : 0;
    __syncthreads();
    tsum[t] += x;
    __syncthreads();
  }
  int run = part[b] + ((t > 0) ? tsum[t - 1] : 0);
#pragma unroll
  for (int q = 0; q < 8; ++q) {
    int i = base + q;
    if (i < n) off[i] = run;
    run += loc[q];
  }
}

__global__ void scatter_kernel(const int* __restrict__ vtx, const int* __restrict__ edg,
                               const int* __restrict__ eoff, const int* __restrict__ voff,
                               int* __restrict__ curE, int* __restrict__ curV,
                               int* __restrict__ evtx, int* __restrict__ vedg, int nnz) {
  int i = blockIdx.x * blockDim.x + threadIdx.x;
  if (i < nnz) {
    int e = edg[i], v = vtx[i];
    int p = atomicAdd(&curE[e], 1);
    evtx[eoff[e] + p] = v;
    int q = atomicAdd(&curV[v], 1);
    vedg[voff[v] + q] = e;
  }
}

// ---------------- GEMM: BK=64, swizzled LDS, dbuf counted-vmcnt, XCD-chunked 1-D grid ----------------
template <int TN>
__global__ __launch_bounds__(256) void gemm_bf16_kernel(
    const bf16* __restrict__ A, const bf16* __restrict__ B,
    bf16* __restrict__ Cb, int M, int K, int ldC, int Nstore) {
  __shared__ bf16 Al[2][128][64];
  __shared__ bf16 Bl[2][TN][64];
  const int bid = blockIdx.x;
  const int cpx = gridDim.x >> 3;
  const int wid = (bid & 7) * cpx + (bid >> 3);
  const int MBLK = (M + 127) >> 7;
  int mIdx, nIdx;
  if (TN == 128) { mIdx = wid >> 2; nIdx = wid & 3; }
  else           { mIdx = wid;      nIdx = 0; }
  if (mIdx >= MBLK) return;
  const int m0 = mIdx * 128;
  const int n0 = nIdx * TN;

  const int t = threadIdx.x;
  const int w = t >> 6, lane = t & 63;
  const int rb = (TN == 128) ? ((w >> 1) * 64) : (w * 32);
  const int cb = (TN == 128) ? ((w & 1) * 64) : 0;
  const int MF = (TN == 128) ? 4 : 2;
  const int lr = lane & 15;
  const int ls = lane >> 4;

  f32x4 acc[(TN == 128) ? 4 : 2][4];
#pragma unroll
  for (int m = 0; m < MF; ++m)
#pragma unroll
    for (int n = 0; n < 4; ++n) acc[m][n] = (f32x4){0.f, 0.f, 0.f, 0.f};

  const int srow8 = lane >> 3;
  const int scol = ((lane & 7) ^ srow8) << 3;

  const bf16* Abase = A + (size_t)m0 * K;
  const bf16* Bbase = B + (size_t)n0 * K;

#define STAGE(tile, bsel)                                                          \
  {                                                                                \
    const int kk_ = (tile) * 64;                                                   \
    _Pragma("unroll")                                                              \
    for (int q = 0; q < 4; ++q) {                                                  \
      const int row = w * 32 + q * 8 + srow8;                                      \
      gload_lds16(Abase + (size_t)row * K + kk_ + scol, &Al[bsel][w*32+q*8][0]);   \
    }                                                                              \
    _Pragma("unroll")                                                              \
    for (int q = 0; q < TN / 32; ++q) {                                            \
      const int row = w * (TN / 4) + q * 8 + srow8;                                \
      gload_lds16(Bbase + (size_t)row * K + kk_ + scol,                            \
                  &Bl[bsel][w * (TN / 4) + q * 8][0]);                             \
    }                                                                              \
  }

  const int NT = K >> 6;
  STAGE(0, 0);
  for (int tt = 0; tt < NT; ++tt) {
    const int cur = tt & 1;
    if (tt + 1 < NT) {
      STAGE(tt + 1, cur ^ 1);
      if (TN == 128) asm volatile("s_waitcnt vmcnt(8)" ::: "memory");
      else           asm volatile("s_waitcnt vmcnt(6)" ::: "memory");
    } else {
      asm volatile("s_waitcnt vmcnt(0)" ::: "memory");
    }
    __builtin_amdgcn_s_barrier();
    __builtin_amdgcn_s_setprio(1);
#pragma unroll
    for (int ks = 0; ks < 2; ++ks) {
      bf16x8 af[(TN == 128) ? 4 : 2], bfr[4];
#pragma unroll
      for (int m = 0; m < MF; ++m) {
        const int R = rb + m * 16 + lr;
        af[m] = *(const bf16x8*)(&Al[cur][R][((ks * 4 + ls) ^ (lr & 7)) << 3]);
      }
#pragma unroll
      for (int n = 0; n < 4; ++n) {
        const int R = cb + n * 16 + lr;
        bfr[n] = *(const bf16x8*)(&Bl[cur][R][((ks * 4 + ls) ^ (lr & 7)) << 3]);
      }
#pragma unroll
      for (int m = 0; m < MF; ++m)
#pragma unroll
        for (int n = 0; n < 4; ++n)
          acc[m][n] = __builtin_amdgcn_mfma_f32_16x16x32_bf16(af[m], bfr[n], acc[m][n], 0, 0, 0);
    }
    __builtin_amdgcn_s_setprio(0);
    __builtin_amdgcn_s_barrier();
  }
#undef STAGE

  const int cr = (lane >> 4) << 2;  // C/D: col = lane&15, row = (lane>>4)*4 + i
  const int cc = lane & 15;
#pragma unroll
  for (int m = 0; m < MF; ++m) {
#pragma unroll
    for (int n = 0; n < 4; ++n) {
      int gc = n0 + cb + n * 16 + cc;
      if (gc >= Nstore) continue;
#pragma unroll
      for (int i = 0; i < 4; ++i) {
        int gr = m0 + rb + m * 16 + cr + i;
        if (gr < M) Cb[(size_t)gr * ldC + gc] = (bf16)acc[m][n][i];
      }
    }
  }
}

// ---------------- wave-per-edge aggregation (bf16, C=512), unroll-2 ----------------
__global__ __launch_bounds__(256) void edge_agg_w(
    const bf16* __restrict__ Y, const int* __restrict__ eoff, const int* __restrict__ evtx,
    const float* __restrict__ degE, bf16* __restrict__ Xe, int nE) {
  const int wv = (blockIdx.x * 256 + threadIdx.x) >> 6;
  if (wv >= nE) return;
  const int lane = threadIdx.x & 63;
  const int beg = eoff[wv], end = eoff[wv + 1];
  const int cnt = end - beg;
  const float scale = (cnt > 0) ? degE[wv] / (float)cnt : 0.f;
  float acc[8] = {0.f, 0.f, 0.f, 0.f, 0.f, 0.f, 0.f, 0.f};
  for (int base = beg; base < end; base += 64) {
    const int nb = min(64, end - base);
    int myidx = (lane < nb) ? evtx[base + lane] : 0;
    int j = 0;
    for (; j + 1 < nb; j += 2) {
      const int i0 = __shfl(myidx, j);
      const int i1 = __shfl(myidx, j + 1);
      bf16x8 v0 = *(const bf16x8*)(Y + (size_t)i0 * 512 + lane * 8);
      bf16x8 v1 = *(const bf16x8*)(Y + (size_t)i1 * 512 + lane * 8);
#pragma unroll
      for (int q = 0; q < 8; ++q) acc[q] += (float)v0[q] + (float)v1[q];
    }
    if (j < nb) {
      const int i0 = __shfl(myidx, j);
      bf16x8 v0 = *(const bf16x8*)(Y + (size_t)i0 * 512 + lane * 8);
#pragma unroll
      for (int q = 0; q < 8; ++q) acc[q] += (float)v0[q];
    }
  }
  bf16x8 o;
#pragma unroll
  for (int q = 0; q < 8; ++q) o[q] = (bf16)(acc[q] * scale);
  *(bf16x8*)(Xe + (size_t)wv * 512 + lane * 8) = o;
}

// ---------------- wave-per-vertex aggregation (bf16, relu, C=512), unroll-2 ----------------
__global__ __launch_bounds__(256) void vtx_agg_w(
    const bf16* __restrict__ Xe, const int* __restrict__ voff, const int* __restrict__ vedg,
    const float* __restrict__ degV, bf16* __restrict__ outB, int nV) {
  const int wv = (blockIdx.x * 256 + threadIdx.x) >> 6;
  if (wv >= nV) return;
  const int lane = threadIdx.x & 63;
  const int beg = voff[wv], end = voff[wv + 1];
  const float dv = degV[wv];
  float acc[8] = {0.f, 0.f, 0.f, 0.f, 0.f, 0.f, 0.f, 0.f};
  for (int base = beg; base < end; base += 64) {
    const int nb = min(64, end - base);
    int myidx = (lane < nb) ? vedg[base + lane] : 0;
    int j = 0;
    for (; j + 1 < nb; j += 2) {
      const int i0 = __shfl(myidx, j);
      const int i1 = __shfl(myidx, j + 1);
      bf16x8 v0 = *(const bf16x8*)(Xe + (size_t)i0 * 512 + lane * 8);
      bf16x8 v1 = *(const bf16x8*)(Xe + (size_t)i1 * 512 + lane * 8);
#pragma unroll
      for (int q = 0; q < 8; ++q) acc[q] += (float)v0[q] + (float)v1[q];
    }
    if (j < nb) {
      const int i0 = __shfl(myidx, j);
      bf16x8 v0 = *(const bf16x8*)(Xe + (size_t)i0 * 512 + lane * 8);
#pragma unroll
      for (int q = 0; q < 8; ++q) acc[q] += (float)v0[q];
    }
  }
  bf16x8 o;
#pragma unroll
  for (int q = 0; q < 8; ++q) o[q] = (bf16)fmaxf(acc[q] * dv, 0.f);
  *(bf16x8*)(outB + (size_t)wv * 512 + lane * 8) = o;
}

// ---------------- layer-3 edge aggregation, octet layout (C=64 padded) ----------------
__global__ __launch_bounds__(256) void edge_agg40_w8(
    const bf16* __restrict__ Y, const int* __restrict__ eoff, const int* __restrict__ evtx,
    const float* __restrict__ degE, bf16* __restrict__ Xe, int nE) {
  const int wv = (blockIdx.x * 256 + threadIdx.x) >> 6;
  if (wv >= nE) return;
  const int lane = threadIdx.x & 63;
  const int g = lane >> 3, c = lane & 7;
  const int beg = eoff[wv], end = eoff[wv + 1];
  const int cnt = end - beg;
  const float scale = (cnt > 0) ? degE[wv] / (float)cnt : 0.f;
  float acc[8] = {0.f, 0.f, 0.f, 0.f, 0.f, 0.f, 0.f, 0.f};
  for (int base = beg; base < end; base += 64) {
    const int nb = min(64, end - base);
    int myidx = (lane < nb) ? evtx[base + lane] : 0;
    for (int inner = 0; inner < 8; ++inner) {
      const int r = inner * 8 + g;
      if (inner * 8 >= nb) break;
      const int ridx = __shfl(myidx, r);
      if (r < nb) {
        bf16x8 v = *(const bf16x8*)(Y + (size_t)ridx * 64 + c * 8);
#pragma unroll
        for (int q = 0; q < 8; ++q) acc[q] += (float)v[q];
      }
    }
  }
#pragma unroll
  for (int o = 8; o < 64; o <<= 1)
#pragma unroll
    for (int q = 0; q < 8; ++q) acc[q] += __shfl_xor(acc[q], o);
  if (lane < 8) {
    bf16x8 o;
#pragma unroll
    for (int q = 0; q < 8; ++q) o[q] = (bf16)(acc[q] * scale);
    *(bf16x8*)(Xe + (size_t)wv * 64 + lane * 8) = o;
  }
}

// ---------------- final vertex aggregation + log_softmax, octet layout ----------------
__global__ __launch_bounds__(256) void vtx_agg_lsm8(
    const bf16* __restrict__ Xe, const int* __restrict__ voff, const int* __restrict__ vedg,
    const float* __restrict__ degV, float* __restrict__ out, int nV) {
  const int wv = (blockIdx.x * 256 + threadIdx.x) >> 6;
  if (wv >= nV) return;
  const int lane = threadIdx.x & 63;
  const int g = lane >> 3, c = lane & 7;
  const int beg = voff[wv], end = voff[wv + 1];
  const float dv = degV[wv];
  float acc[8] = {0.f, 0.f, 0.f, 0.f, 0.f, 0.f, 0.f, 0.f};
  for (int base = beg; base < end; base += 64) {
    const int nb = min(64, end - base);
    int myidx = (lane < nb) ? vedg[base + lane] : 0;
    for (int inner = 0; inner < 8; ++inner) {
      const int r = inner * 8 + g;
      if (inner * 8 >= nb) break;
      const int ridx = __shfl(myidx, r);
      if (r < nb) {
        bf16x8 v = *(const bf16x8*)(Xe + (size_t)ridx * 64 + c * 8);
#pragma unroll
        for (int q = 0; q < 8; ++q) acc[q] += (float)v[q];
      }
    }
  }
#pragma unroll
  for (int o = 8; o < 64; o <<= 1)
#pragma unroll
    for (int q = 0; q < 8; ++q) acc[q] += __shfl_xor(acc[q], o);
  float l[8];
#pragma unroll
  for (int q = 0; q < 8; ++q) l[q] = acc[q] * dv;
  float lm = -3.4e38f;
  if (c < 5) {
#pragma unroll
    for (int q = 0; q < 8; ++q) lm = fmaxf(lm, l[q]);
  }
#pragma unroll
  for (int o = 1; o < 8; o <<= 1) lm = fmaxf(lm, __shfl_xor(lm, o));
  float ls = 0.f;
  if (c < 5) {
#pragma unroll
    for (int q = 0; q < 8; ++q) ls += expf(l[q] - lm);
  }
#pragma unroll
  for (int o = 1; o < 8; o <<= 1) ls += __shfl_xor(ls, o);
  const float lg = logf(ls);
  if (lane < 5) {
    f32x8 w;
#pragma unroll
    for (int q = 0; q < 8; ++q) w[q] = l[q] - lm - lg;
    *(f32x8*)(out + (size_t)wv * 40 + lane * 8) = w;
  }
}

extern "C" void kernel_launch(void* const* d_in, const int* in_sizes, int n_in,
                              void* d_out, int out_size, void* d_ws, size_t ws_size,
                              hipStream_t stream) {
  (void)in_sizes; (void)n_in; (void)out_size; (void)ws_size;
  const float* X = (const float*)d_in[0];
  const int* vertex = (const int*)d_in[1];
  const int* edges = (const int*)d_in[2];
  const float* W1 = (const float*)d_in[3];
  const float* W2 = (const float*)d_in[4];
  const float* Wout = (const float*)d_in[5];
  const float* degE = (const float*)d_in[6];
  const float* degV = (const float*)d_in[7];
  float* out = (float*)d_out;

  char* ws = (char*)d_ws;
  size_t off = 0;
  auto alloc = [&](size_t bytes) -> void* {
    void* p = ws + off;
    off += (bytes + 255) & ~(size_t)255;
    return p;
  };
  bf16* Xb  = (bf16*)alloc((size_t)N_NODES * 512 * sizeof(bf16));   // vertex features H
  bf16* XeB = (bf16*)alloc((size_t)N_EDGES_C * 512 * sizeof(bf16)); // edge agg of H
  bf16* YeB = (bf16*)alloc((size_t)N_EDGES_C * 512 * sizeof(bf16)); // XeB @ W
  bf16* Y40b  = (bf16*)alloc((size_t)N_NODES * 64 * sizeof(bf16));
  bf16* Xe40b = (bf16*)alloc((size_t)N_EDGES_C * 64 * sizeof(bf16));
  bf16* Wt1 = (bf16*)alloc((size_t)512 * 512 * sizeof(bf16));
  bf16* Wt2 = (bf16*)alloc((size_t)512 * 512 * sizeof(bf16));
  bf16* Wt3 = (bf16*)alloc((size_t)64 * 512 * sizeof(bf16));
  int* eoff = (int*)alloc((N_EDGES_C + 1) * sizeof(int));
  int* voff = (int*)alloc((N_NODES + 1) * sizeof(int));
  int* evtx = (int*)alloc((size_t)NNZ_C * sizeof(int));
  int* vedg = (int*)alloc((size_t)NNZ_C * sizeof(int));
  int* cnts = (int*)alloc((size_t)(2 * (N_EDGES_C + N_NODES)) * sizeof(int));
  int* cntE = cnts;
  int* cntV = cnts + N_EDGES_C;
  int* curE = cnts + N_EDGES_C + N_NODES;
  int* curV = cnts + 2 * N_EDGES_C + N_NODES;
  int* partE = (int*)alloc(64 * sizeof(int));
  int* partV = (int*)alloc(64 * sizeof(int));

  hipMemsetAsync(cnts, 0, (size_t)(2 * (N_EDGES_C + N_NODES)) * sizeof(int), stream);

  prep_conv<<<PREP_TOTAL, 256, 0, stream>>>(
      W1, W2, Wout, X, Wt1, Wt2, Wt3, Xb, vertex, edges, cntV, cntE);

  const int nbE = (N_EDGES_C + SCHUNK - 1) / SCHUNK;  // 13
  const int nbV = (N_NODES + SCHUNK - 1) / SCHUNK;    // 25
  scan_part2<<<nbE + nbV, 256, 0, stream>>>(cntE, cntV, partE, partV, nbE);
  scan_mid2<<<1, 128, 0, stream>>>(partE, partV, eoff, voff, nbE, nbV);
  scan_final2<<<nbE + nbV, 256, 0, stream>>>(cntE, cntV, partE, partV, eoff, voff, nbE);

  scatter_kernel<<<(NNZ_C + 255) / 256, 256, 0, stream>>>(vertex, edges, eoff, voff,
                                                          curE, curV, evtx, vedg, NNZ_C);

  const int MBV = (N_NODES + 127) / 128;          // 391 (vertex-side GEMM, layer 3)
  const int MBE = (N_EDGES_C + 127) / 128;        // 196 (edge-side GEMM, layers 1-2)
  const int GE512 = ((MBE * 4 + 7) / 8) * 8;      // 784
  const int GV64  = ((MBV + 7) / 8) * 8;          // 392

  // ---- layer 1: edge_agg(X) -> GEMM on 25K edge rows -> vtx_agg ----
  // segment_mean(X@W)*degE == (segment_mean(X)*degE)@W  (linearity)
  edge_agg_w<<<(N_EDGES_C + 3) / 4, 256, 0, stream>>>(Xb, eoff, evtx, degE, XeB, N_EDGES_C);
  gemm_bf16_kernel<128><<<GE512, 256, 0, stream>>>(XeB, Wt1, YeB, N_EDGES_C, 512, 512, 512);
  vtx_agg_w<<<(N_NODES + 3) / 4, 256, 0, stream>>>(YeB, voff, vedg, degV, Xb, N_NODES);

  // ---- layer 2 ----
  edge_agg_w<<<(N_EDGES_C + 3) / 4, 256, 0, stream>>>(Xb, eoff, evtx, degE, XeB, N_EDGES_C);
  gemm_bf16_kernel<128><<<GE512, 256, 0, stream>>>(XeB, Wt2, YeB, N_EDGES_C, 512, 512, 512);
  vtx_agg_w<<<(N_NODES + 3) / 4, 256, 0, stream>>>(YeB, voff, vedg, degV, Xb, N_NODES);

  // ---- layer 3 (old order: GEMM on 50K first, then narrow 64-wide aggs) ----
  gemm_bf16_kernel<64><<<GV64, 256, 0, stream>>>(Xb, Wt3, Y40b, N_NODES, 512, 64, 64);
  edge_agg40_w8<<<(N_EDGES_C + 3) / 4, 256, 0, stream>>>(Y40b, eoff, evtx, degE, Xe40b, N_EDGES_C);
  vtx_agg_lsm8<<<(N_NODES + 3) / 4, 256, 0, stream>>>(Xe40b, voff, vedg, degV, out, N_NODES);
}